// Round 10
// baseline (538.502 us; speedup 1.0000x reference)
//
#include <hip/hip_runtime.h>
#include <hip/hip_cooperative_groups.h>
#include <math.h>

namespace cg = cooperative_groups;

// Problem constants
#define BB 4
#define TT 4096
#define CC 1024
#define HS 64
#define KSEL 2048
#define NSPL 16   // KV splits per row-block
#define SWLOG 8   // split width = 256
#define SW 256
#define NBLK 256  // 1 block/CU -> cooperative co-residency guaranteed

typedef float f32x4 __attribute__((ext_vector_type(4)));
typedef short short8 __attribute__((ext_vector_type(8)));

__device__ __forceinline__ unsigned short f2bf(float f) {
  union { float f; unsigned int u; } c;
  c.f = f;
  const unsigned int u = c.u;
  return (unsigned short)((u + 0x7FFFu + ((u >> 16) & 1u)) >> 16);  // RTNE
}

__device__ __forceinline__ unsigned cvtpk(float lo, float hi) {
  unsigned r;
  asm("v_cvt_pk_bf16_f32 %0, %1, %2" : "=v"(r) : "v"(lo), "v"(hi));
  return r;
}

// ===========================================================================
// MEGA: whole pipeline in one cooperative kernel, 256 blocks x 256 threads.
// Phases separated by grid.sync() (replaces ~6 kernel-launch gaps).
// ===========================================================================
__global__ __launch_bounds__(256) void mega(
    const float* __restrict__ x, const float* __restrict__ Wq,
    const float* __restrict__ Wk, const float* __restrict__ Wv,
    float* __restrict__ out, float* __restrict__ xsum, float* __restrict__ rs,
    int* __restrict__ flag, unsigned short* __restrict__ wbf,
    unsigned short* __restrict__ qbf, unsigned short* __restrict__ kbf,
    unsigned short* __restrict__ vtbf, int* __restrict__ idxp,
    float* __restrict__ pl, float* __restrict__ pacc) {
  __shared__ __align__(16) unsigned char SM[20480];
  cg::grid_group grid = cg::this_grid();
  const int blk = blockIdx.x;
  const int tid = threadIdx.x;
  const int wid = tid >> 6, lane = tid & 63;
  const int lhi = lane >> 4, llo = lane & 15;

  // ---------------- Phase 0: conv_w + zero xsum ----------------
  {
    const int gid = blk * 256 + tid;  // 0..65535
    if (gid < 1024) ((float4*)xsum)[gid] = make_float4(0.f, 0.f, 0.f, 0.f);
    if (gid < 24576) {
      const int kt = gid / 768;
      const int rem = gid - kt * 768;
      const int nt = rem >> 6, ln = rem & 63;
      const int col = nt * 16 + (ln & 15);
      const float* W = (col < 64) ? Wq : ((col < 128) ? Wk : Wv);
      const int cl = col & 63;
      const int k0 = kt * 32 + (ln >> 4) * 8;
      unsigned short tmp[8];
#pragma unroll
      for (int i = 0; i < 8; i++) tmp[i] = f2bf(W[(size_t)(k0 + i) * HS + cl]);
      uint4 o;
      o.x = tmp[0] | ((unsigned)tmp[1] << 16);
      o.y = tmp[2] | ((unsigned)tmp[3] << 16);
      o.z = tmp[4] | ((unsigned)tmp[5] << 16);
      o.w = tmp[6] | ((unsigned)tmp[7] << 16);
      *(uint4*)(wbf + (size_t)gid * 8) = o;
    }
  }
  __threadfence();
  grid.sync();

  // ---------------- Phase A: fused projection (2 x 32-row tiles) ----------
  {
    unsigned short* Xs = (unsigned short*)SM;  // [32][256] swizzled, 16KB
    float* xsred = (float*)(SM + 16384);       // [4][256], 4KB
    const int cl = tid & 63, rg = tid >> 6;
    const int mt = wid >> 1, nh = wid & 1;
#pragma unroll 1
    for (int it = 0; it < 2; ++it) {
      const int rblk = blk * 2 + it;  // 0..511
      const size_t r0 = (size_t)rblk * 32;
      const int bidx = rblk >> 7;
      f32x4 acc[6];
#pragma unroll
      for (int n = 0; n < 6; n++) acc[n] = (f32x4){0.f, 0.f, 0.f, 0.f};
      float4 pf[8];
#pragma unroll
      for (int rr = 0; rr < 8; rr++)
        pf[rr] = *(const float4*)(x + (r0 + rg * 8 + rr) * CC + cl * 4);

      for (int ch = 0; ch < 4; ch++) {
        float ps0 = 0.f, ps1 = 0.f, ps2 = 0.f, ps3 = 0.f;
#pragma unroll
        for (int rr = 0; rr < 8; rr++) {
          const int row = rg * 8 + rr;
          float4 v = pf[rr];
          ps0 += v.x; ps1 += v.y; ps2 += v.z; ps3 += v.w;
          *(uint2*)((char*)Xs + row * 512 + ((((cl >> 1) ^ (row & 7))) << 4) +
                    ((cl & 1) << 3)) =
              make_uint2(cvtpk(v.x, v.y), cvtpk(v.z, v.w));
        }
        xsred[rg * 256 + cl * 4 + 0] = ps0;
        xsred[rg * 256 + cl * 4 + 1] = ps1;
        xsred[rg * 256 + cl * 4 + 2] = ps2;
        xsred[rg * 256 + cl * 4 + 3] = ps3;
        __syncthreads();
        if (ch < 3) {
#pragma unroll
          for (int rr = 0; rr < 8; rr++)
            pf[rr] = *(const float4*)(x + (r0 + rg * 8 + rr) * CC +
                                      (ch + 1) * 256 + cl * 4);
        }
        atomicAdd(&xsum[bidx * CC + ch * 256 + tid],
                  xsred[tid] + xsred[256 + tid] + xsred[512 + tid] +
                      xsred[768 + tid]);
        const int row = mt * 16 + llo;
#pragma unroll
        for (int ktl = 0; ktl < 8; ktl++) {
          short8 af =
              *(const short8*)((const char*)Xs + row * 512 +
                               ((((ktl << 2) + lhi) ^ (row & 7)) << 4));
          const unsigned short* bp =
              wbf + (((size_t)(ch * 8 + ktl) * 12 + nh * 6) * 64 + lane) * 8;
#pragma unroll
          for (int n = 0; n < 6; n++) {
            short8 bf = *(const short8*)(bp + n * 64 * 8);
            acc[n] = __builtin_amdgcn_mfma_f32_16x16x32_bf16(af, bf, acc[n],
                                                             0, 0, 0);
          }
        }
        __syncthreads();
      }
      const int rbg = (int)r0 + mt * 16 + lhi * 4;
#pragma unroll
      for (int n = 0; n < 6; n++) {
        const int col = (nh * 6 + n) * 16 + llo;
        const int mat = col >> 6, cl2 = col & 63;
        if (mat == 0) {
#pragma unroll
          for (int r = 0; r < 4; r++)
            qbf[(size_t)(rbg + r) * HS + cl2] = f2bf(acc[n][r] * 0.03125f);
        } else if (mat == 1) {
#pragma unroll
          for (int r = 0; r < 4; r++)
            kbf[(size_t)(rbg + r) * HS + cl2] = f2bf(acc[n][r]);
        } else {
          const int bb = rbg >> 12, tloc = rbg & (TT - 1);
          *(uint2*)(vtbf + ((size_t)bb * HS + cl2) * TT + tloc) = make_uint2(
              cvtpk(acc[n][0], acc[n][1]), cvtpk(acc[n][2], acc[n][3]));
        }
      }
      __syncthreads();
    }
  }
  __threadfence();
  grid.sync();

  // ---------------- Phase B: w = Wq(Wk^T xsum); rs = x . w ----------------
  {
    float* xsl = (float*)SM;   // 1024
    float* kred = xsl + 1024;  // 256
    float* ksl = kred + 256;   // 64
    float* wl = ksl + 64;      // 1024
    const int g0 = blk * 2;    // both iterations share batch
    const int b = g0 >> 7;
    *(float4*)(xsl + tid * 4) = *(const float4*)(xsum + b * CC + tid * 4);
    __syncthreads();
    {
      float s = 0.f;
      const float* wkp = Wk + (size_t)(wid * 256) * HS + lane;
      for (int c = 0; c < 256; c++)
        s += xsl[wid * 256 + c] * wkp[(size_t)c * HS];
      kred[wid * 64 + lane] = s;
    }
    __syncthreads();
    if (tid < 64)
      ksl[tid] = kred[tid] + kred[64 + tid] + kred[128 + tid] + kred[192 + tid];
    __syncthreads();
#pragma unroll
    for (int p = 0; p < 4; p++) {
      const int c = p * 256 + tid;
      const float* wqp = Wq + (size_t)c * HS;
      float s = 0.f;
#pragma unroll
      for (int d4 = 0; d4 < 16; d4++) {
        float4 a = *(const float4*)(wqp + d4 * 4);
        float4 kk = *(const float4*)(ksl + d4 * 4);
        s += a.x * kk.x + a.y * kk.y + a.z * kk.z + a.w * kk.w;
      }
      wl[c] = s;
    }
    __syncthreads();
#pragma unroll 1
    for (int it = 0; it < 2; ++it) {
      const size_t row = (size_t)(g0 + it) * 32 + (tid >> 3);
      const int qu = tid & 7;
      const float* xr = x + row * CC + qu * 128;
      const float* wr = wl + qu * 128;
      float s = 0.f;
      for (int e = 0; e < 32; e++) {
        float4 v = *(const float4*)(xr + e * 4);
        float4 w4 = *(const float4*)(wr + e * 4);
        s += v.x * w4.x + v.y * w4.y + v.z * w4.z + v.w * w4.w;
      }
      s += __shfl_xor(s, 1);
      s += __shfl_xor(s, 2);
      s += __shfl_xor(s, 4);
      if (qu == 0) rs[row] = s;
    }
  }
  __threadfence();
  grid.sync();

  // ---------------- Phase C: rank (2 x 32 candidates) ----------------
  {
    float* rl = (float*)SM;  // 4096 floats
    const int g0 = blk * 2;
    const int b = g0 >> 7;
    const float* rsb = rs + (size_t)b * TT;
    for (int e = tid; e < TT / 4; e += 256)
      *(float4*)(rl + e * 4) = *(const float4*)(rsb + e * 4);
    __syncthreads();
#pragma unroll 1
    for (int it = 0; it < 2; ++it) {
      const int chunk = (g0 + it) & 127;
      const int cand = tid >> 3, qu = tid & 7;
      const int t = chunk * 32 + cand;
      const float my = rl[t];
      int cnt = 0;
      for (int e = 0; e < 128; e++) {
        const int s = qu * 512 + e * 4;
        float4 v = *(const float4*)(rl + s);
        cnt += (v.x > my) || (v.x == my && (s + 0) < t);
        cnt += (v.y > my) || (v.y == my && (s + 1) < t);
        cnt += (v.z > my) || (v.z == my && (s + 2) < t);
        cnt += (v.w > my) || (v.w == my && (s + 3) < t);
      }
      cnt += __shfl_xor(cnt, 1);
      cnt += __shfl_xor(cnt, 2);
      cnt += __shfl_xor(cnt, 4);
      if (qu == 0) flag[(size_t)b * TT + t] = (cnt < KSEL) ? 1 : 0;
    }
  }
  __threadfence();
  grid.sync();

  // ---------------- Phase D: compact (blocks 0..3) ----------------
  if (blk < BB) {
    int* wsum = (int*)SM;
    int* woff = wsum + 4;
    const int* fb = flag + (size_t)blk * TT;
    const int base = tid * 16;
    int f[16];
    int cnt = 0;
#pragma unroll
    for (int e4 = 0; e4 < 4; e4++) {
      int4 v = *(const int4*)(fb + base + e4 * 4);
      f[e4 * 4 + 0] = v.x; f[e4 * 4 + 1] = v.y;
      f[e4 * 4 + 2] = v.z; f[e4 * 4 + 3] = v.w;
      cnt += v.x + v.y + v.z + v.w;
    }
    int sc = cnt;
#pragma unroll
    for (int d = 1; d < 64; d <<= 1) {
      int v = __shfl_up(sc, d);
      if (lane >= d) sc += v;
    }
    if (lane == 63) wsum[wid] = sc;
    __syncthreads();
    if (tid == 0) {
      int a = 0;
#pragma unroll
      for (int w = 0; w < 4; w++) { woff[w] = a; a += wsum[w]; }
    }
    __syncthreads();
    int pos = woff[wid] + sc - cnt;
#pragma unroll
    for (int e = 0; e < 16; e++)
      if (f[e]) idxp[(size_t)blk * KSEL + (pos++)] = base + e;
  }
  __threadfence();
  grid.sync();

  // ---------------- Phase E: attention (4 split-units per wave) ----------
  {
    unsigned short* P = (unsigned short*)SM;
    unsigned short* Pw = P + wid * 32 * 40;
#pragma unroll 1
    for (int half = 0; half < 4; half++) {
      const int u = (blk * 4 + wid) + half * 1024;  // 0..4095
      const int b = u & 3;
      const int rb = (u >> 2) & 63;
      const int sp = u >> 8;  // 0..15
      const size_t rbase = (size_t)b * KSEL + rb * 32;
      const int tmaxblk = idxp[rbase + 31];
      const int jlo = sp << SWLOG;
      if (jlo > tmaxblk) continue;

      const int trow0 = idxp[rbase + llo];
      const int trow1 = idxp[rbase + 16 + llo];
      short8 qf[2][2];
      {
        const unsigned short* qp0 =
            qbf + ((size_t)b * TT + trow0) * HS + lhi * 8;
        const unsigned short* qp1 =
            qbf + ((size_t)b * TT + trow1) * HS + lhi * 8;
        qf[0][0] = *(const short8*)(qp0);
        qf[0][1] = *(const short8*)(qp0 + 32);
        qf[1][0] = *(const short8*)(qp1);
        qf[1][1] = *(const short8*)(qp1 + 32);
      }
      f32x4 o[2][4];
#pragma unroll
      for (int mtt = 0; mtt < 2; mtt++)
#pragma unroll
        for (int n = 0; n < 4; n++) o[mtt][n] = (f32x4){0.f, 0.f, 0.f, 0.f};
      float lsum[2] = {0.f, 0.f};

      const unsigned short* kb = kbf + (size_t)b * TT * HS;
      const unsigned short* vb = vtbf + (size_t)b * HS * TT;
      const int jend = min(tmaxblk + 1, jlo + SW);

      auto loadK = [&](int j0, short8* K) {
        const unsigned short* kp = kb + (size_t)(j0 + llo) * HS + lhi * 8;
        K[0] = *(const short8*)(kp);
        K[1] = *(const short8*)(kp + 32);
        K[2] = *(const short8*)(kp + 16 * HS);
        K[3] = *(const short8*)(kp + 16 * HS + 32);
      };
      auto loadV = [&](int j0, short8* V) {
        const unsigned short* vp = vb + (size_t)llo * TT + j0 + lhi * 8;
        V[0] = *(const short8*)(vp);
        V[1] = *(const short8*)(vp + 16 * TT);
        V[2] = *(const short8*)(vp + 32 * TT);
        V[3] = *(const short8*)(vp + 48 * TT);
      };

      auto body = [&](int j0, const short8* K, const short8* V) {
        f32x4 sc[2][2];
#pragma unroll
        for (int mtt = 0; mtt < 2; mtt++) {
          f32x4 a = (f32x4){0.f, 0.f, 0.f, 0.f};
          a = __builtin_amdgcn_mfma_f32_16x16x32_bf16(K[0], qf[mtt][0], a, 0, 0, 0);
          a = __builtin_amdgcn_mfma_f32_16x16x32_bf16(K[1], qf[mtt][1], a, 0, 0, 0);
          sc[mtt][0] = a;
          f32x4 c = (f32x4){0.f, 0.f, 0.f, 0.f};
          c = __builtin_amdgcn_mfma_f32_16x16x32_bf16(K[2], qf[mtt][0], c, 0, 0, 0);
          c = __builtin_amdgcn_mfma_f32_16x16x32_bf16(K[3], qf[mtt][1], c, 0, 0, 0);
          sc[mtt][1] = c;
        }
#pragma unroll
        for (int mtt = 0; mtt < 2; mtt++) {
          const int tr = (mtt == 0) ? trow0 : trow1;
          float p[8];
#pragma unroll
          for (int kt = 0; kt < 2; kt++)
#pragma unroll
            for (int r = 0; r < 4; r++) {
              const int kk = j0 + kt * 16 + lhi * 4 + r;
              const float e = __expf(sc[mtt][kt][r]);
              p[kt * 4 + r] = (kk <= tr) ? e : 0.f;
            }
          lsum[mtt] += ((p[0] + p[1]) + (p[2] + p[3])) +
                       ((p[4] + p[5]) + (p[6] + p[7]));
          *(uint2*)&Pw[(mtt * 16 + llo) * 40 + lhi * 4] =
              make_uint2(cvtpk(p[0], p[1]), cvtpk(p[2], p[3]));
          *(uint2*)&Pw[(mtt * 16 + llo) * 40 + 16 + lhi * 4] =
              make_uint2(cvtpk(p[4], p[5]), cvtpk(p[6], p[7]));
        }
        short8 pa0 = *(const short8*)&Pw[llo * 40 + lhi * 8];
        short8 pa1 = *(const short8*)&Pw[(16 + llo) * 40 + lhi * 8];
        o[0][0] = __builtin_amdgcn_mfma_f32_16x16x32_bf16(pa0, V[0], o[0][0], 0, 0, 0);
        o[1][0] = __builtin_amdgcn_mfma_f32_16x16x32_bf16(pa1, V[0], o[1][0], 0, 0, 0);
        o[0][1] = __builtin_amdgcn_mfma_f32_16x16x32_bf16(pa0, V[1], o[0][1], 0, 0, 0);
        o[1][1] = __builtin_amdgcn_mfma_f32_16x16x32_bf16(pa1, V[1], o[1][1], 0, 0, 0);
        o[0][2] = __builtin_amdgcn_mfma_f32_16x16x32_bf16(pa0, V[2], o[0][2], 0, 0, 0);
        o[1][2] = __builtin_amdgcn_mfma_f32_16x16x32_bf16(pa1, V[2], o[1][2], 0, 0, 0);
        o[0][3] = __builtin_amdgcn_mfma_f32_16x16x32_bf16(pa0, V[3], o[0][3], 0, 0, 0);
        o[1][3] = __builtin_amdgcn_mfma_f32_16x16x32_bf16(pa1, V[3], o[1][3], 0, 0, 0);
      };

      int j0 = jlo;
      short8 ka[4], kb2[4], va[4], vb2[4];
      loadK(j0, ka);
      loadV(j0, va);
      for (;;) {
        if (j0 + 32 < jend) { loadK(j0 + 32, kb2); loadV(j0 + 32, vb2); }
        body(j0, ka, va);
        j0 += 32;
        if (j0 >= jend) break;
        if (j0 + 32 < jend) { loadK(j0 + 32, ka); loadV(j0 + 32, va); }
        body(j0, kb2, vb2);
        j0 += 32;
        if (j0 >= jend) break;
      }

      lsum[0] += __shfl_xor(lsum[0], 16);
      lsum[0] += __shfl_xor(lsum[0], 32);
      lsum[1] += __shfl_xor(lsum[1], 16);
      lsum[1] += __shfl_xor(lsum[1], 32);
      if (lane < 16) {
        pl[(rbase + llo) * NSPL + sp] = lsum[0];
        pl[(rbase + 16 + llo) * NSPL + sp] = lsum[1];
      }
#pragma unroll
      for (int mtt = 0; mtt < 2; mtt++)
#pragma unroll
        for (int r = 0; r < 4; r++) {
          const size_t rowi = rbase + mtt * 16 + lhi * 4 + r;
#pragma unroll
          for (int n = 0; n < 4; n++)
            pacc[(rowi * NSPL + sp) * HS + n * 16 + llo] = o[mtt][n][r];
        }
    }
  }
  __threadfence();
  grid.sync();

  // ---------------- Phase F: combine + normalize (2 x 16 rows) -----------
  {
#pragma unroll 1
    for (int it = 0; it < 2; ++it) {
      const int r = tid >> 4, dg = tid & 15;
      const size_t rowi = (size_t)(blk * 2 + it) * 16 + r;
      const int t_r = idxp[rowi];
      const int ns = (t_r >> SWLOG) + 1;
      float L = 0.f;
      float o0 = 0.f, o1 = 0.f, o2 = 0.f, o3 = 0.f;
      for (int s = 0; s < ns; s++) {
        L += pl[rowi * NSPL + s];
        float4 a = *(const float4*)(pacc + (rowi * NSPL + s) * HS + dg * 4);
        o0 += a.x; o1 += a.y; o2 += a.z; o3 += a.w;
      }
      const float invl = 1.0f / L;
      *(float4*)(out + rowi * HS + dg * 4) =
          make_float4(o0 * invl, o1 * invl, o2 * invl, o3 * invl);
    }
  }
}

// ===========================================================================
// FALLBACK: proven R8 multi-kernel pipeline (used iff co-op launch rejected).
// ===========================================================================
__global__ __launch_bounds__(256) void conv_w_fb(
    const float* __restrict__ Wq, const float* __restrict__ Wk,
    const float* __restrict__ Wv, unsigned short* __restrict__ wbf,
    float* __restrict__ xsum) {
  const int gid = blockIdx.x * 256 + threadIdx.x;
  if (gid < 1024) ((float4*)xsum)[gid] = make_float4(0.f, 0.f, 0.f, 0.f);
  const int kt = gid / 768;
  const int rem = gid - kt * 768;
  const int nt = rem >> 6, lane = rem & 63;
  const int col = nt * 16 + (lane & 15);
  const float* W = (col < 64) ? Wq : ((col < 128) ? Wk : Wv);
  const int cl = col & 63;
  const int k0 = kt * 32 + (lane >> 4) * 8;
  unsigned short tmp[8];
#pragma unroll
  for (int i = 0; i < 8; i++) tmp[i] = f2bf(W[(size_t)(k0 + i) * HS + cl]);
  uint4 o;
  o.x = tmp[0] | ((unsigned)tmp[1] << 16);
  o.y = tmp[2] | ((unsigned)tmp[3] << 16);
  o.z = tmp[4] | ((unsigned)tmp[5] << 16);
  o.w = tmp[6] | ((unsigned)tmp[7] << 16);
  *(uint4*)(wbf + (size_t)gid * 8) = o;
}

__global__ __launch_bounds__(256) void fusedproj_fb(
    const float* __restrict__ x, const unsigned short* __restrict__ wbf,
    float* __restrict__ xsum, unsigned short* __restrict__ qbf,
    unsigned short* __restrict__ kbf, unsigned short* __restrict__ vtbf) {
  __shared__ unsigned short Xs[16][256];
  __shared__ float xsred[4][256];
  const int rb = blockIdx.x;
  const size_t r0 = (size_t)rb * 16;
  const int tid = threadIdx.x;
  const int wid = tid >> 6, lane = tid & 63;
  const int lhi = lane >> 4, llo = lane & 15;
  const int cl = tid & 63, rg = tid >> 6;
  const int bidx = rb >> 8;
  f32x4 acc[3];
#pragma unroll
  for (int n = 0; n < 3; n++) acc[n] = (f32x4){0.f, 0.f, 0.f, 0.f};
  float4 pf[4];
#pragma unroll
  for (int rr = 0; rr < 4; rr++)
    pf[rr] = *(const float4*)(x + (r0 + rg * 4 + rr) * CC + cl * 4);
  for (int ch = 0; ch < 4; ch++) {
    float ps0 = 0.f, ps1 = 0.f, ps2 = 0.f, ps3 = 0.f;
#pragma unroll
    for (int rr = 0; rr < 4; rr++) {
      const int row = rg * 4 + rr;
      float4 v = pf[rr];
      ps0 += v.x; ps1 += v.y; ps2 += v.z; ps3 += v.w;
      *(uint2*)((char*)&Xs[0][0] + row * 512 +
                ((((cl >> 1) ^ (row & 7))) << 4) + ((cl & 1) << 3)) =
          make_uint2(cvtpk(v.x, v.y), cvtpk(v.z, v.w));
    }
    xsred[rg][cl * 4 + 0] = ps0;
    xsred[rg][cl * 4 + 1] = ps1;
    xsred[rg][cl * 4 + 2] = ps2;
    xsred[rg][cl * 4 + 3] = ps3;
    __syncthreads();
    if (ch < 3) {
#pragma unroll
      for (int rr = 0; rr < 4; rr++)
        pf[rr] = *(const float4*)(x + (r0 + rg * 4 + rr) * CC +
                                  (ch + 1) * 256 + cl * 4);
    }
    atomicAdd(&xsum[bidx * CC + ch * 256 + tid],
              xsred[0][tid] + xsred[1][tid] + xsred[2][tid] + xsred[3][tid]);
#pragma unroll
    for (int ktl = 0; ktl < 8; ktl++) {
      short8 af = *(const short8*)((const char*)&Xs[0][0] + llo * 512 +
                                   ((((ktl << 2) + lhi) ^ (llo & 7)) << 4));
      const unsigned short* bp =
          wbf + (((size_t)(ch * 8 + ktl) * 12 + wid * 3) * 64 + lane) * 8;
#pragma unroll
      for (int n = 0; n < 3; n++) {
        short8 bf = *(const short8*)(bp + n * 64 * 8);
        acc[n] = __builtin_amdgcn_mfma_f32_16x16x32_bf16(af, bf, acc[n], 0, 0, 0);
      }
    }
    __syncthreads();
  }
  const int rbg = (int)r0 + lhi * 4;
#pragma unroll
  for (int n = 0; n < 3; n++) {
    const int col = (wid * 3 + n) * 16 + llo;
    const int mat = col >> 6, cl2 = col & 63;
    if (mat == 0) {
#pragma unroll
      for (int r = 0; r < 4; r++)
        qbf[(size_t)(rbg + r) * HS + cl2] = f2bf(acc[n][r] * 0.03125f);
    } else if (mat == 1) {
#pragma unroll
      for (int r = 0; r < 4; r++)
        kbf[(size_t)(rbg + r) * HS + cl2] = f2bf(acc[n][r]);
    } else {
      const int bb = rbg >> 12, tloc = rbg & (TT - 1);
      *(uint2*)(vtbf + ((size_t)bb * HS + cl2) * TT + tloc) =
          make_uint2(cvtpk(acc[n][0], acc[n][1]), cvtpk(acc[n][2], acc[n][3]));
    }
  }
}

__global__ __launch_bounds__(512) void rowsums_fb(
    const float* __restrict__ x, const float* __restrict__ Wq,
    const float* __restrict__ Wk, const float* __restrict__ xsum,
    float* __restrict__ rs) {
  __shared__ float xsl[CC];
  __shared__ float kred[8][HS];
  __shared__ float ksl[HS];
  __shared__ float wl[CC];
  const int g = blockIdx.x;
  const int tid = threadIdx.x;
  const int b = g >> 6;
  *(float2*)(xsl + tid * 2) = *(const float2*)(xsum + b * CC + tid * 2);
  __syncthreads();
  {
    const int g8 = tid >> 6, d = tid & 63;
    const float* wkp = Wk + (size_t)(g8 * 128) * HS + d;
    float s = 0.f;
    for (int c = 0; c < 128; c++) s += xsl[g8 * 128 + c] * wkp[(size_t)c * HS];
    kred[g8][d] = s;
  }
  __syncthreads();
  if (tid < 64) {
    float s = 0.f;
#pragma unroll
    for (int g8 = 0; g8 < 8; g8++) s += kred[g8][tid];
    ksl[tid] = s;
  }
  __syncthreads();
#pragma unroll
  for (int p = 0; p < 2; p++) {
    const int c = tid * 2 + p;
    const float* wqp = Wq + (size_t)c * HS;
    float s = 0.f;
#pragma unroll
    for (int d4 = 0; d4 < 16; d4++) {
      float4 a = *(const float4*)(wqp + d4 * 4);
      float4 kk = *(const float4*)(ksl + d4 * 4);
      s += a.x * kk.x + a.y * kk.y + a.z * kk.z + a.w * kk.w;
    }
    wl[c] = s;
  }
  __syncthreads();
  const size_t row = (size_t)g * 64 + (tid >> 3);
  const int qu = tid & 7;
  const float* xr = x + row * CC + qu * 128;
  const float* wr = wl + qu * 128;
  float s = 0.f;
  for (int e = 0; e < 32; e++) {
    float4 v = *(const float4*)(xr + e * 4);
    float4 w4 = *(const float4*)(wr + e * 4);
    s += v.x * w4.x + v.y * w4.y + v.z * w4.z + v.w * w4.w;
  }
  s += __shfl_xor(s, 1);
  s += __shfl_xor(s, 2);
  s += __shfl_xor(s, 4);
  if (qu == 0) rs[row] = s;
}

__global__ __launch_bounds__(256) void rankk_fb(const float* __restrict__ rs,
                                                int* __restrict__ flag) {
  __shared__ float rl[TT];
  const int g = blockIdx.x;
  const int b = g >> 7, chunk = g & 127;
  const int tid = threadIdx.x;
  const float* rsb = rs + (size_t)b * TT;
  for (int e = tid; e < TT / 4; e += 256)
    *(float4*)(rl + e * 4) = *(const float4*)(rsb + e * 4);
  __syncthreads();
  const int cand = tid >> 3, qu = tid & 7;
  const int t = chunk * 32 + cand;
  const float my = rl[t];
  int cnt = 0;
  for (int e = 0; e < 128; e++) {
    const int s = qu * 512 + e * 4;
    float4 v = *(const float4*)(rl + s);
    cnt += (v.x > my) || (v.x == my && (s + 0) < t);
    cnt += (v.y > my) || (v.y == my && (s + 1) < t);
    cnt += (v.z > my) || (v.z == my && (s + 2) < t);
    cnt += (v.w > my) || (v.w == my && (s + 3) < t);
  }
  cnt += __shfl_xor(cnt, 1);
  cnt += __shfl_xor(cnt, 2);
  cnt += __shfl_xor(cnt, 4);
  if (qu == 0) flag[(size_t)b * TT + t] = (cnt < KSEL) ? 1 : 0;
}

__global__ __launch_bounds__(256) void compact_fb(const int* __restrict__ flag,
                                                  int* __restrict__ idx) {
  __shared__ int wsum[4];
  __shared__ int woff[4];
  const int b = blockIdx.x;
  const int tid = threadIdx.x;
  const int wid = tid >> 6, lane = tid & 63;
  const int* fb = flag + (size_t)b * TT;
  const int base = tid * 16;
  int f[16];
  int cnt = 0;
#pragma unroll
  for (int e4 = 0; e4 < 4; e4++) {
    int4 v = *(const int4*)(fb + base + e4 * 4);
    f[e4 * 4 + 0] = v.x; f[e4 * 4 + 1] = v.y;
    f[e4 * 4 + 2] = v.z; f[e4 * 4 + 3] = v.w;
    cnt += v.x + v.y + v.z + v.w;
  }
  int sc = cnt;
#pragma unroll
  for (int d = 1; d < 64; d <<= 1) {
    int v = __shfl_up(sc, d);
    if (lane >= d) sc += v;
  }
  if (lane == 63) wsum[wid] = sc;
  __syncthreads();
  if (tid == 0) {
    int a = 0;
#pragma unroll
    for (int w = 0; w < 4; w++) { woff[w] = a; a += wsum[w]; }
  }
  __syncthreads();
  int pos = woff[wid] + sc - cnt;
#pragma unroll
  for (int e = 0; e < 16; e++)
    if (f[e]) idx[(size_t)b * KSEL + (pos++)] = base + e;
}

__global__ __launch_bounds__(256) void attn_fb(
    const unsigned short* __restrict__ qbf,
    const unsigned short* __restrict__ kbf,
    const unsigned short* __restrict__ vtbf, const int* __restrict__ idx,
    float* __restrict__ pl, float* __restrict__ pacc) {
  __shared__ unsigned short P_lds[4][32][40];
  const int rb = blockIdx.x;
  const int zz = blockIdx.y;
  const int b = blockIdx.z;
  const int tid = threadIdx.x;
  const int wid = tid >> 6, lane = tid & 63;
  const int s = zz * 4 + wid;
  const size_t rbase = (size_t)b * KSEL + rb * 32;
  const int tmaxblk = idx[rbase + 31];
  const int jlo = s << SWLOG;
  if (jlo > tmaxblk) return;
  const int lhi = lane >> 4, llo = lane & 15;
  const int trow0 = idx[rbase + llo];
  const int trow1 = idx[rbase + 16 + llo];
  short8 qf[2][2];
  {
    const unsigned short* qp0 = qbf + ((size_t)b * TT + trow0) * HS + lhi * 8;
    const unsigned short* qp1 = qbf + ((size_t)b * TT + trow1) * HS + lhi * 8;
    qf[0][0] = *(const short8*)(qp0);
    qf[0][1] = *(const short8*)(qp0 + 32);
    qf[1][0] = *(const short8*)(qp1);
    qf[1][1] = *(const short8*)(qp1 + 32);
  }
  f32x4 o[2][4];
#pragma unroll
  for (int mtt = 0; mtt < 2; mtt++)
#pragma unroll
    for (int n = 0; n < 4; n++) o[mtt][n] = (f32x4){0.f, 0.f, 0.f, 0.f};
  float lsum[2] = {0.f, 0.f};
  const unsigned short* kb = kbf + (size_t)b * TT * HS;
  const unsigned short* vb = vtbf + (size_t)b * HS * TT;
  const int jend = min(tmaxblk + 1, jlo + SW);
  auto loadK = [&](int j0, short8* K) {
    const unsigned short* kp = kb + (size_t)(j0 + llo) * HS + lhi * 8;
    K[0] = *(const short8*)(kp);
    K[1] = *(const short8*)(kp + 32);
    K[2] = *(const short8*)(kp + 16 * HS);
    K[3] = *(const short8*)(kp + 16 * HS + 32);
  };
  auto loadV = [&](int j0, short8* V) {
    const unsigned short* vp = vb + (size_t)llo * TT + j0 + lhi * 8;
    V[0] = *(const short8*)(vp);
    V[1] = *(const short8*)(vp + 16 * TT);
    V[2] = *(const short8*)(vp + 32 * TT);
    V[3] = *(const short8*)(vp + 48 * TT);
  };
  auto body = [&](int j0, const short8* K, const short8* V) {
    f32x4 sc[2][2];
#pragma unroll
    for (int mtt = 0; mtt < 2; mtt++) {
      f32x4 a = (f32x4){0.f, 0.f, 0.f, 0.f};
      a = __builtin_amdgcn_mfma_f32_16x16x32_bf16(K[0], qf[mtt][0], a, 0, 0, 0);
      a = __builtin_amdgcn_mfma_f32_16x16x32_bf16(K[1], qf[mtt][1], a, 0, 0, 0);
      sc[mtt][0] = a;
      f32x4 c = (f32x4){0.f, 0.f, 0.f, 0.f};
      c = __builtin_amdgcn_mfma_f32_16x16x32_bf16(K[2], qf[mtt][0], c, 0, 0, 0);
      c = __builtin_amdgcn_mfma_f32_16x16x32_bf16(K[3], qf[mtt][1], c, 0, 0, 0);
      sc[mtt][1] = c;
    }
#pragma unroll
    for (int mtt = 0; mtt < 2; mtt++) {
      const int tr = (mtt == 0) ? trow0 : trow1;
      float p[8];
#pragma unroll
      for (int kt = 0; kt < 2; kt++)
#pragma unroll
        for (int r = 0; r < 4; r++) {
          const int kk = j0 + kt * 16 + lhi * 4 + r;
          const float e = __expf(sc[mtt][kt][r]);
          p[kt * 4 + r] = (kk <= tr) ? e : 0.f;
        }
      lsum[mtt] += ((p[0] + p[1]) + (p[2] + p[3])) +
                   ((p[4] + p[5]) + (p[6] + p[7]));
      *(uint2*)&P_lds[wid][mtt * 16 + llo][lhi * 4] =
          make_uint2(cvtpk(p[0], p[1]), cvtpk(p[2], p[3]));
      *(uint2*)&P_lds[wid][mtt * 16 + llo][16 + lhi * 4] =
          make_uint2(cvtpk(p[4], p[5]), cvtpk(p[6], p[7]));
    }
    short8 pa0 = *(const short8*)&P_lds[wid][llo][lhi * 8];
    short8 pa1 = *(const short8*)&P_lds[wid][16 + llo][lhi * 8];
    o[0][0] = __builtin_amdgcn_mfma_f32_16x16x32_bf16(pa0, V[0], o[0][0], 0, 0, 0);
    o[1][0] = __builtin_amdgcn_mfma_f32_16x16x32_bf16(pa1, V[0], o[1][0], 0, 0, 0);
    o[0][1] = __builtin_amdgcn_mfma_f32_16x16x32_bf16(pa0, V[1], o[0][1], 0, 0, 0);
    o[1][1] = __builtin_amdgcn_mfma_f32_16x16x32_bf16(pa1, V[1], o[1][1], 0, 0, 0);
    o[0][2] = __builtin_amdgcn_mfma_f32_16x16x32_bf16(pa0, V[2], o[0][2], 0, 0, 0);
    o[1][2] = __builtin_amdgcn_mfma_f32_16x16x32_bf16(pa1, V[2], o[1][2], 0, 0, 0);
    o[0][3] = __builtin_amdgcn_mfma_f32_16x16x32_bf16(pa0, V[3], o[0][3], 0, 0, 0);
    o[1][3] = __builtin_amdgcn_mfma_f32_16x16x32_bf16(pa1, V[3], o[1][3], 0, 0, 0);
  };
  int j0 = jlo;
  short8 ka[4], kb2[4], va[4], vb2[4];
  loadK(j0, ka);
  loadV(j0, va);
  for (;;) {
    if (j0 + 32 < jend) { loadK(j0 + 32, kb2); loadV(j0 + 32, vb2); }
    body(j0, ka, va);
    j0 += 32;
    if (j0 >= jend) break;
    if (j0 + 32 < jend) { loadK(j0 + 32, ka); loadV(j0 + 32, va); }
    body(j0, kb2, vb2);
    j0 += 32;
    if (j0 >= jend) break;
  }
  lsum[0] += __shfl_xor(lsum[0], 16);
  lsum[0] += __shfl_xor(lsum[0], 32);
  lsum[1] += __shfl_xor(lsum[1], 16);
  lsum[1] += __shfl_xor(lsum[1], 32);
  if (lane < 16) {
    pl[(rbase + llo) * NSPL + s] = lsum[0];
    pl[(rbase + 16 + llo) * NSPL + s] = lsum[1];
  }
#pragma unroll
  for (int mtt = 0; mtt < 2; mtt++)
#pragma unroll
    for (int r = 0; r < 4; r++) {
      const size_t rowi = rbase + mtt * 16 + lhi * 4 + r;
#pragma unroll
      for (int n = 0; n < 4; n++)
        pacc[(rowi * NSPL + s) * HS + n * 16 + llo] = o[mtt][n][r];
    }
}

__global__ __launch_bounds__(256) void combine_fb(
    const float* __restrict__ pl, const float* __restrict__ pacc,
    const int* __restrict__ idx, float* __restrict__ out) {
  const int b = blockIdx.x;
  const int i0 = blockIdx.y * 32;
  const int tid = threadIdx.x;
  const int r = tid >> 3, dg = tid & 7;
  const size_t rowi = (size_t)b * KSEL + i0 + r;
  const int t_r = idx[rowi];
  const int ns = (t_r >> SWLOG) + 1;
  float L = 0.f;
  float o[8] = {0.f, 0.f, 0.f, 0.f, 0.f, 0.f, 0.f, 0.f};
  for (int s = 0; s < ns; s++) {
    L += pl[rowi * NSPL + s];
    const float* pa = pacc + (rowi * NSPL + s) * HS + dg * 8;
    float4 a0 = *(const float4*)(pa);
    float4 a1 = *(const float4*)(pa + 4);
    o[0] += a0.x; o[1] += a0.y; o[2] += a0.z; o[3] += a0.w;
    o[4] += a1.x; o[5] += a1.y; o[6] += a1.z; o[7] += a1.w;
  }
  const float invl = 1.0f / L;
  float* op = out + rowi * HS + dg * 8;
  *(float4*)(op) = make_float4(o[0] * invl, o[1] * invl, o[2] * invl, o[3] * invl);
  *(float4*)(op + 4) = make_float4(o[4] * invl, o[5] * invl, o[6] * invl, o[7] * invl);
}

// ---------------------------------------------------------------------------
extern "C" void kernel_launch(void* const* d_in, const int* in_sizes, int n_in,
                              void* d_out, int out_size, void* d_ws,
                              size_t ws_size, hipStream_t stream) {
  const float* x = (const float*)d_in[0];
  const float* Wq = (const float*)d_in[1];
  const float* Wk = (const float*)d_in[2];
  const float* Wv = (const float*)d_in[3];
  float* out = (float*)d_out;

  float* wsf = (float*)d_ws;
  // pacc (attn phase) overlaps selection-phase scratch (all dead by then).
  float* pacc = wsf;                                      // 8,388,608 f
  float* xsum = wsf;                                      // 4,096 f
  float* rs = xsum + 4096;                                // 16,384 f
  int* flag = (int*)(rs + 16384);                         // 16,384 i
  unsigned short* wbf = (unsigned short*)(flag + 16384);  // 196,608 us
  unsigned short* qbf = (unsigned short*)(pacc + 8388608);
  unsigned short* kbf = qbf + 1048576;
  unsigned short* vtbf = kbf + 1048576;
  int* idxp = (int*)(vtbf + 1048576);
  float* pl = (float*)(idxp + 8192);

  void* args[] = {(void*)&x,    (void*)&Wq,   (void*)&Wk,   (void*)&Wv,
                  (void*)&out,  (void*)&xsum, (void*)&rs,   (void*)&flag,
                  (void*)&wbf,  (void*)&qbf,  (void*)&kbf,  (void*)&vtbf,
                  (void*)&idxp, (void*)&pl,   (void*)&pacc};
  hipError_t err = hipLaunchCooperativeKernel((const void*)mega, dim3(NBLK),
                                              dim3(256), args, 0, stream);
  if (err != hipSuccess) {
    (void)hipGetLastError();  // clear sticky error, use proven pipeline
    conv_w_fb<<<96, 256, 0, stream>>>(Wq, Wk, Wv, wbf, xsum);
    fusedproj_fb<<<1024, 256, 0, stream>>>(x, wbf, xsum, qbf, kbf, vtbf);
    rowsums_fb<<<256, 512, 0, stream>>>(x, Wq, Wk, xsum, rs);
    rankk_fb<<<512, 256, 0, stream>>>(rs, flag);
    compact_fb<<<BB, 256, 0, stream>>>(flag, idxp);
    attn_fb<<<dim3(64, 4, BB), 256, 0, stream>>>(qbf, kbf, vtbf, idxp, pl, pacc);
    combine_fb<<<dim3(BB, 64), 256, 0, stream>>>(pl, pacc, idxp, out);
  }
}

// Round 11
// 365.748 us; speedup vs baseline: 1.4723x; 1.4723x over previous
//
#include <hip/hip_runtime.h>
#include <math.h>

// Problem constants
#define BB 4
#define TT 4096
#define CC 1024
#define HS 64
#define KSEL 2048
#define NSPL 16   // KV splits per row-block
#define SWLOG 8   // split width = 256
#define SW 256

typedef float f32x4 __attribute__((ext_vector_type(4)));
typedef short short8 __attribute__((ext_vector_type(8)));

__device__ __forceinline__ unsigned short f2bf(float f) {
  union { float f; unsigned int u; } c;
  c.f = f;
  const unsigned int u = c.u;
  return (unsigned short)((u + 0x7FFFu + ((u >> 16) & 1u)) >> 16);  // RTNE
}

// packed f32x2 -> bf16x2 (RTNE), single HW instruction
__device__ __forceinline__ unsigned cvtpk(float lo, float hi) {
  unsigned r;
  asm("v_cvt_pk_bf16_f32 %0, %1, %2" : "=v"(r) : "v"(lo), "v"(hi));
  return r;
}

// ---------------------------------------------------------------------------
// conv_w: Wq|Wk|Wv fp32 -> bf16 B-fragment layout; also zeroes xsum and the
// two device-side completion counters (replaces memset dispatches).
// 96 blocks x 256 thr (gid exactly covers 24576 conversion slots).
// ---------------------------------------------------------------------------
__global__ __launch_bounds__(256) void conv_w(const float* __restrict__ Wq,
                                              const float* __restrict__ Wk,
                                              const float* __restrict__ Wv,
                                              unsigned short* __restrict__ wbf,
                                              float* __restrict__ xsum,
                                              int* __restrict__ cnts) {
  const int gid = blockIdx.x * 256 + threadIdx.x;  // 0..24575
  if (gid < 1024) ((float4*)xsum)[gid] = make_float4(0.f, 0.f, 0.f, 0.f);
  if (gid < 66) ((int4*)cnts)[gid] = make_int4(0, 0, 0, 0);  // 264 ints
  const int kt = gid / 768;
  const int rem = gid - kt * 768;
  const int nt = rem >> 6, lane = rem & 63;
  const int col = nt * 16 + (lane & 15);
  const float* W = (col < 64) ? Wq : ((col < 128) ? Wk : Wv);
  const int cl = col & 63;
  const int k0 = kt * 32 + (lane >> 4) * 8;
  unsigned short tmp[8];
#pragma unroll
  for (int i = 0; i < 8; i++) tmp[i] = f2bf(W[(size_t)(k0 + i) * HS + cl]);
  uint4 o;
  o.x = tmp[0] | ((unsigned)tmp[1] << 16);
  o.y = tmp[2] | ((unsigned)tmp[3] << 16);
  o.z = tmp[4] | ((unsigned)tmp[5] << 16);
  o.w = tmp[6] | ((unsigned)tmp[7] << 16);
  *(uint4*)(wbf + (size_t)gid * 8) = o;
}

// ---------------------------------------------------------------------------
// fusedproj (R6-proven): reads x ONCE. 1024 blocks x 16 rows. Per 256-col
// chunk: stage bf16 into XOR-swizzled LDS, atomicAdd fp32 column sums into
// xsum, MFMA against wbf (L2-hot). Writes q (prescaled 2^-5), k row-major
// bf16, V transposed vt[b][d][t].
// ---------------------------------------------------------------------------
#define PR 16
__global__ __launch_bounds__(256) void fusedproj(
    const float* __restrict__ x, const unsigned short* __restrict__ wbf,
    float* __restrict__ xsum, unsigned short* __restrict__ qbf,
    unsigned short* __restrict__ kbf, unsigned short* __restrict__ vtbf) {
  __shared__ unsigned short Xs[PR][256];  // 8 KB, granule-XOR-swizzled
  __shared__ float xsred[4][256];
  const int rb = blockIdx.x;  // 1024 blocks
  const size_t r0 = (size_t)rb * PR;
  const int tid = threadIdx.x;
  const int wid = tid >> 6, lane = tid & 63;
  const int lhi = lane >> 4, llo = lane & 15;
  const int cl = tid & 63, rg = tid >> 6;
  const int bidx = rb >> 8;

  f32x4 acc[3];
#pragma unroll
  for (int n = 0; n < 3; n++) acc[n] = (f32x4){0.f, 0.f, 0.f, 0.f};

  float4 pf[4];
#pragma unroll
  for (int rr = 0; rr < 4; rr++)
    pf[rr] = *(const float4*)(x + (r0 + rg * 4 + rr) * CC + cl * 4);

  for (int ch = 0; ch < 4; ch++) {
    float ps0 = 0.f, ps1 = 0.f, ps2 = 0.f, ps3 = 0.f;
#pragma unroll
    for (int rr = 0; rr < 4; rr++) {
      const int row = rg * 4 + rr;
      float4 v = pf[rr];
      ps0 += v.x; ps1 += v.y; ps2 += v.z; ps3 += v.w;
      *(uint2*)((char*)&Xs[0][0] + row * 512 +
                ((((cl >> 1) ^ (row & 7))) << 4) + ((cl & 1) << 3)) =
          make_uint2(cvtpk(v.x, v.y), cvtpk(v.z, v.w));
    }
    xsred[rg][cl * 4 + 0] = ps0;
    xsred[rg][cl * 4 + 1] = ps1;
    xsred[rg][cl * 4 + 2] = ps2;
    xsred[rg][cl * 4 + 3] = ps3;
    __syncthreads();
    if (ch < 3) {
#pragma unroll
      for (int rr = 0; rr < 4; rr++)
        pf[rr] = *(const float4*)(x + (r0 + rg * 4 + rr) * CC +
                                  (ch + 1) * 256 + cl * 4);
    }
    atomicAdd(&xsum[bidx * CC + ch * 256 + tid],
              xsred[0][tid] + xsred[1][tid] + xsred[2][tid] + xsred[3][tid]);
#pragma unroll
    for (int ktl = 0; ktl < 8; ktl++) {
      short8 af = *(const short8*)((const char*)&Xs[0][0] + llo * 512 +
                                   ((((ktl << 2) + lhi) ^ (llo & 7)) << 4));
      const unsigned short* bp =
          wbf + (((size_t)(ch * 8 + ktl) * 12 + wid * 3) * 64 + lane) * 8;
#pragma unroll
      for (int n = 0; n < 3; n++) {
        short8 bf = *(const short8*)(bp + n * 64 * 8);
        acc[n] = __builtin_amdgcn_mfma_f32_16x16x32_bf16(af, bf, acc[n], 0, 0, 0);
      }
    }
    __syncthreads();
  }
  const int rbg = (int)r0 + lhi * 4;
#pragma unroll
  for (int n = 0; n < 3; n++) {
    const int col = (wid * 3 + n) * 16 + llo;
    const int mat = col >> 6, cl2 = col & 63;
    if (mat == 0) {
#pragma unroll
      for (int r = 0; r < 4; r++)
        qbf[(size_t)(rbg + r) * HS + cl2] = f2bf(acc[n][r] * 0.03125f);
    } else if (mat == 1) {
#pragma unroll
      for (int r = 0; r < 4; r++)
        kbf[(size_t)(rbg + r) * HS + cl2] = f2bf(acc[n][r]);
    } else {
      const int bb = rbg >> 12, tloc = rbg & (TT - 1);
      *(uint2*)(vtbf + ((size_t)bb * HS + cl2) * TT + tloc) =
          make_uint2(cvtpk(acc[n][0], acc[n][1]), cvtpk(acc[n][2], acc[n][3]));
    }
  }
}

// ---------------------------------------------------------------------------
// rowsums_x (R6-proven): per-block prologue computes w = Wq (Wk^T xsum);
// main: rs[row] = x[row] . w (fp32 exact). 256 blocks x 512 thr.
// ---------------------------------------------------------------------------
__global__ __launch_bounds__(512) void rowsums_x(
    const float* __restrict__ x, const float* __restrict__ Wq,
    const float* __restrict__ Wk, const float* __restrict__ xsum,
    float* __restrict__ rs) {
  __shared__ float xsl[CC];
  __shared__ float kred[8][HS];
  __shared__ float ksl[HS];
  __shared__ float wl[CC];
  const int g = blockIdx.x;
  const int tid = threadIdx.x;
  const int b = g >> 6;
  *(float2*)(xsl + tid * 2) = *(const float2*)(xsum + b * CC + tid * 2);
  __syncthreads();
  {
    const int g8 = tid >> 6, d = tid & 63;
    const float* wkp = Wk + (size_t)(g8 * 128) * HS + d;
    float s = 0.f;
    for (int c = 0; c < 128; c++) s += xsl[g8 * 128 + c] * wkp[(size_t)c * HS];
    kred[g8][d] = s;
  }
  __syncthreads();
  if (tid < 64) {
    float s = 0.f;
#pragma unroll
    for (int g8 = 0; g8 < 8; g8++) s += kred[g8][tid];
    ksl[tid] = s;
  }
  __syncthreads();
#pragma unroll
  for (int p = 0; p < 2; p++) {
    const int c = tid * 2 + p;
    const float* wqp = Wq + (size_t)c * HS;
    float s = 0.f;
#pragma unroll
    for (int d4 = 0; d4 < 16; d4++) {
      float4 a = *(const float4*)(wqp + d4 * 4);
      float4 kk = *(const float4*)(ksl + d4 * 4);
      s += a.x * kk.x + a.y * kk.y + a.z * kk.z + a.w * kk.w;
    }
    wl[c] = s;
  }
  __syncthreads();
  const size_t row = (size_t)g * 64 + (tid >> 3);
  const int qu = tid & 7;
  const float* xr = x + row * CC + qu * 128;
  const float* wr = wl + qu * 128;
  float s = 0.f;
  for (int e = 0; e < 32; e++) {
    float4 v = *(const float4*)(xr + e * 4);
    float4 w4 = *(const float4*)(wr + e * 4);
    s += v.x * w4.x + v.y * w4.y + v.z * w4.z + v.w * w4.w;
  }
  s += __shfl_xor(s, 1);
  s += __shfl_xor(s, 2);
  s += __shfl_xor(s, 4);
  if (qu == 0) rs[row] = s;
}

// ---------------------------------------------------------------------------
// rankk_compact: rank (512 blocks; flag[t] = t in top-2048, ties by index),
// then the LAST block per batch (device atomic counter) compacts the flags
// into ascending idx in its tail -- removes the separate compact dispatch.
// ---------------------------------------------------------------------------
__global__ __launch_bounds__(256) void rankk_compact(
    const float* __restrict__ rs, int* __restrict__ flag,
    int* __restrict__ idxp, int* __restrict__ cnt_rk) {
  __shared__ float rl[TT];
  __shared__ int lastFlag;
  const int g = blockIdx.x;  // B*128
  const int b = g >> 7, chunk = g & 127;
  const int tid = threadIdx.x;
  const int wid = tid >> 6, lane = tid & 63;
  const float* rsb = rs + (size_t)b * TT;
  for (int e = tid; e < TT / 4; e += 256)
    *(float4*)(rl + e * 4) = *(const float4*)(rsb + e * 4);
  __syncthreads();
  {
    const int cand = tid >> 3, qu = tid & 7;
    const int t = chunk * 32 + cand;
    const float my = rl[t];
    int cnt = 0;
    for (int e = 0; e < 128; e++) {
      const int s = qu * 512 + e * 4;
      float4 v = *(const float4*)(rl + s);
      cnt += (v.x > my) || (v.x == my && (s + 0) < t);
      cnt += (v.y > my) || (v.y == my && (s + 1) < t);
      cnt += (v.z > my) || (v.z == my && (s + 2) < t);
      cnt += (v.w > my) || (v.w == my && (s + 3) < t);
    }
    cnt += __shfl_xor(cnt, 1);
    cnt += __shfl_xor(cnt, 2);
    cnt += __shfl_xor(cnt, 4);
    if (qu == 0) flag[(size_t)b * TT + t] = (cnt < KSEL) ? 1 : 0;
  }
  // release: flags visible before counter bump
  __threadfence();
  __syncthreads();
  if (tid == 0) lastFlag = (atomicAdd(&cnt_rk[b], 1) == 127);
  __syncthreads();
  if (!lastFlag) return;
  __threadfence();  // acquire: see all batch flags
  // ---- compact tail (wave shfl-scan, proven in R8) ----
  __shared__ int wsum[4];
  __shared__ int woff[4];
  const int* fb = flag + (size_t)b * TT;
  const int base = tid * 16;
  int f[16];
  int cnt = 0;
#pragma unroll
  for (int e4 = 0; e4 < 4; e4++) {
    int4 v = *(const int4*)(fb + base + e4 * 4);
    f[e4 * 4 + 0] = v.x; f[e4 * 4 + 1] = v.y;
    f[e4 * 4 + 2] = v.z; f[e4 * 4 + 3] = v.w;
    cnt += v.x + v.y + v.z + v.w;
  }
  int sc = cnt;
#pragma unroll
  for (int d = 1; d < 64; d <<= 1) {
    int v = __shfl_up(sc, d);
    if (lane >= d) sc += v;
  }
  if (lane == 63) wsum[wid] = sc;
  __syncthreads();
  if (tid == 0) {
    int a = 0;
#pragma unroll
    for (int w = 0; w < 4; w++) { woff[w] = a; a += wsum[w]; }
  }
  __syncthreads();
  int pos = woff[wid] + sc - cnt;
#pragma unroll
  for (int e = 0; e < 16; e++)
    if (f[e]) idxp[(size_t)b * KSEL + (pos++)] = base + e;
}

// ---------------------------------------------------------------------------
// attn_mfma (R6-proven inner loop) + fused combine: swapped-operand QK^T +
// no-max softmax; partials -> pl/pacc; the LAST active split-wave per
// (b,rb) row-block combines (plain sum) and writes normalized out.
// grid (rb=64, zz=4, b=4); wave = one KV split.
// ---------------------------------------------------------------------------
struct KF { short8 a0, a1, b0, b1; };
struct VF { short8 v0, v1, v2, v3; };

__global__ __launch_bounds__(256) void attn_mfma(
    const unsigned short* __restrict__ qbf,
    const unsigned short* __restrict__ kbf,
    const unsigned short* __restrict__ vtbf, const int* __restrict__ idx,
    float* __restrict__ pl, float* __restrict__ pacc,
    int* __restrict__ cnt_at, float* __restrict__ out) {
  __shared__ unsigned short P_lds[4][32][40];
  const int rb = blockIdx.x;
  const int zz = blockIdx.y;
  const int b = blockIdx.z;
  const int tid = threadIdx.x;
  const int wid = tid >> 6, lane = tid & 63;
  const int s = zz * 4 + wid;  // split 0..15
  const size_t rbase = (size_t)b * KSEL + rb * 32;
  const int tmaxblk = idx[rbase + 31];
  const int jlo = s << SWLOG;
  if (jlo > tmaxblk) return;

  const int lhi = lane >> 4, llo = lane & 15;
  const int trow0 = idx[rbase + llo];
  const int trow1 = idx[rbase + 16 + llo];
  short8 qf[2][2];
  {
    const unsigned short* qp0 = qbf + ((size_t)b * TT + trow0) * HS + lhi * 8;
    const unsigned short* qp1 = qbf + ((size_t)b * TT + trow1) * HS + lhi * 8;
    qf[0][0] = *(const short8*)(qp0);
    qf[0][1] = *(const short8*)(qp0 + 32);
    qf[1][0] = *(const short8*)(qp1);
    qf[1][1] = *(const short8*)(qp1 + 32);
  }
  f32x4 o[2][4];
#pragma unroll
  for (int mtt = 0; mtt < 2; mtt++)
#pragma unroll
    for (int n = 0; n < 4; n++) o[mtt][n] = (f32x4){0.f, 0.f, 0.f, 0.f};
  float lsum[2] = {0.f, 0.f};

  const unsigned short* kb = kbf + (size_t)b * TT * HS;
  const unsigned short* vb = vtbf + (size_t)b * HS * TT;
  const int jend = min(tmaxblk + 1, jlo + SW);

  auto loadK = [&](int j0) {
    KF K;
    const unsigned short* kp = kb + (size_t)(j0 + llo) * HS + lhi * 8;
    K.a0 = *(const short8*)(kp);
    K.a1 = *(const short8*)(kp + 32);
    K.b0 = *(const short8*)(kp + 16 * HS);
    K.b1 = *(const short8*)(kp + 16 * HS + 32);
    return K;
  };
  auto loadV = [&](int j0) {
    VF V;
    const unsigned short* vp = vb + (size_t)llo * TT + j0 + lhi * 8;
    V.v0 = *(const short8*)(vp);
    V.v1 = *(const short8*)(vp + 16 * TT);
    V.v2 = *(const short8*)(vp + 32 * TT);
    V.v3 = *(const short8*)(vp + 48 * TT);
    return V;
  };

  auto body = [&](int j0, const KF& K, const VF& V) {
    f32x4 sc[2][2];
#pragma unroll
    for (int mtt = 0; mtt < 2; mtt++) {
      f32x4 a = (f32x4){0.f, 0.f, 0.f, 0.f};
      a = __builtin_amdgcn_mfma_f32_16x16x32_bf16(K.a0, qf[mtt][0], a, 0, 0, 0);
      a = __builtin_amdgcn_mfma_f32_16x16x32_bf16(K.a1, qf[mtt][1], a, 0, 0, 0);
      sc[mtt][0] = a;
      f32x4 c = (f32x4){0.f, 0.f, 0.f, 0.f};
      c = __builtin_amdgcn_mfma_f32_16x16x32_bf16(K.b0, qf[mtt][0], c, 0, 0, 0);
      c = __builtin_amdgcn_mfma_f32_16x16x32_bf16(K.b1, qf[mtt][1], c, 0, 0, 0);
      sc[mtt][1] = c;
    }
#pragma unroll
    for (int mtt = 0; mtt < 2; mtt++) {
      const int tr = (mtt == 0) ? trow0 : trow1;
      float p[8];
#pragma unroll
      for (int kt = 0; kt < 2; kt++)
#pragma unroll
        for (int r = 0; r < 4; r++) {
          const int kk = j0 + kt * 16 + lhi * 4 + r;
          const float e = __expf(sc[mtt][kt][r]);
          p[kt * 4 + r] = (kk <= tr) ? e : 0.f;
        }
      lsum[mtt] += ((p[0] + p[1]) + (p[2] + p[3])) +
                   ((p[4] + p[5]) + (p[6] + p[7]));
      *(uint2*)&P_lds[wid][mtt * 16 + llo][lhi * 4] =
          make_uint2(cvtpk(p[0], p[1]), cvtpk(p[2], p[3]));
      *(uint2*)&P_lds[wid][mtt * 16 + llo][16 + lhi * 4] =
          make_uint2(cvtpk(p[4], p[5]), cvtpk(p[6], p[7]));
    }
    short8 pa0 = *(const short8*)&P_lds[wid][llo][lhi * 8];
    short8 pa1 = *(const short8*)&P_lds[wid][16 + llo][lhi * 8];
    o[0][0] = __builtin_amdgcn_mfma_f32_16x16x32_bf16(pa0, V.v0, o[0][0], 0, 0, 0);
    o[1][0] = __builtin_amdgcn_mfma_f32_16x16x32_bf16(pa1, V.v0, o[1][0], 0, 0, 0);
    o[0][1] = __builtin_amdgcn_mfma_f32_16x16x32_bf16(pa0, V.v1, o[0][1], 0, 0, 0);
    o[1][1] = __builtin_amdgcn_mfma_f32_16x16x32_bf16(pa1, V.v1, o[1][1], 0, 0, 0);
    o[0][2] = __builtin_amdgcn_mfma_f32_16x16x32_bf16(pa0, V.v2, o[0][2], 0, 0, 0);
    o[1][2] = __builtin_amdgcn_mfma_f32_16x16x32_bf16(pa1, V.v2, o[1][2], 0, 0, 0);
    o[0][3] = __builtin_amdgcn_mfma_f32_16x16x32_bf16(pa0, V.v3, o[0][3], 0, 0, 0);
    o[1][3] = __builtin_amdgcn_mfma_f32_16x16x32_bf16(pa1, V.v3, o[1][3], 0, 0, 0);
  };

  int j0 = jlo;
  KF ka = loadK(j0), kb2;
  VF va = loadV(j0), vb2;
  for (;;) {
    if (j0 + 32 < jend) { kb2 = loadK(j0 + 32); vb2 = loadV(j0 + 32); }
    body(j0, ka, va);
    j0 += 32;
    if (j0 >= jend) break;
    if (j0 + 32 < jend) { ka = loadK(j0 + 32); va = loadV(j0 + 32); }
    body(j0, kb2, vb2);
    j0 += 32;
    if (j0 >= jend) break;
  }

  // streaming partial writes (combine is a plain sum)
  lsum[0] += __shfl_xor(lsum[0], 16);
  lsum[0] += __shfl_xor(lsum[0], 32);
  lsum[1] += __shfl_xor(lsum[1], 16);
  lsum[1] += __shfl_xor(lsum[1], 32);
  if (lane < 16) {
    pl[(rbase + llo) * NSPL + s] = lsum[0];
    pl[(rbase + 16 + llo) * NSPL + s] = lsum[1];
  }
#pragma unroll
  for (int mtt = 0; mtt < 2; mtt++)
#pragma unroll
    for (int r = 0; r < 4; r++) {
      const size_t rowi = rbase + mtt * 16 + lhi * 4 + r;
#pragma unroll
      for (int n = 0; n < 4; n++)
        pacc[(rowi * NSPL + s) * HS + n * 16 + llo] = o[mtt][n][r];
    }

  // ---- fused combine: last active split-wave of this (b,rb) merges ----
  __threadfence();  // release partials
  int old = 0;
  if (lane == 0) old = atomicAdd(&cnt_at[b * 64 + rb], 1);
  old = __shfl(old, 0);
  const int nact = (tmaxblk >> SWLOG) + 1;
  if (old != nact - 1) return;
  __threadfence();  // acquire all partials
#pragma unroll 1
  for (int r = 0; r < 32; ++r) {
    const size_t rowi = rbase + r;
    const int nsr = (idx[rowi] >> SWLOG) + 1;
    float L = 0.f;
    float osum = 0.f;
    for (int ss = 0; ss < nsr; ++ss) {
      L += pl[rowi * NSPL + ss];                       // broadcast load
      osum += pacc[(rowi * NSPL + ss) * HS + lane];    // coalesced 256B
    }
    out[rowi * HS + lane] = osum / L;
  }
}

// ---------------------------------------------------------------------------
extern "C" void kernel_launch(void* const* d_in, const int* in_sizes, int n_in,
                              void* d_out, int out_size, void* d_ws,
                              size_t ws_size, hipStream_t stream) {
  const float* x = (const float*)d_in[0];
  const float* Wq = (const float*)d_in[1];
  const float* Wk = (const float*)d_in[2];
  const float* Wv = (const float*)d_in[3];
  float* out = (float*)d_out;

  float* wsf = (float*)d_ws;
  // pacc (attn phase) overlaps selection-phase scratch (dead by then).
  float* pacc = wsf;                                      // 8,388,608 f
  float* xsum = wsf;                                      // 4,096 f
  float* rs = xsum + 4096;                                // 16,384 f
  int* flag = (int*)(rs + 16384);                         // 16,384 i
  unsigned short* wbf = (unsigned short*)(flag + 16384);  // 196,608 us
  // Live through attn:
  unsigned short* qbf = (unsigned short*)(pacc + 8388608);  // 1,048,576 us
  unsigned short* kbf = qbf + 1048576;                      // 1,048,576 us
  unsigned short* vtbf = kbf + 1048576;                     // 1,048,576 us
  int* idxp = (int*)(vtbf + 1048576);                       // 8,192 i
  float* pl = (float*)(idxp + 8192);                        // 131,072 f
  int* cnts = (int*)(pl + 131072);  // 264 i: [0..3]=rank, [8..263]=attn
  int* cnt_rk = cnts;
  int* cnt_at = cnts + 8;

  conv_w<<<96, 256, 0, stream>>>(Wq, Wk, Wv, wbf, xsum, cnts);
  fusedproj<<<1024, 256, 0, stream>>>(x, wbf, xsum, qbf, kbf, vtbf);
  rowsums_x<<<256, 512, 0, stream>>>(x, Wq, Wk, xsum, rs);
  rankk_compact<<<512, 256, 0, stream>>>(rs, flag, idxp, cnt_rk);
  attn_mfma<<<dim3(64, 4, BB), 256, 0, stream>>>(qbf, kbf, vtbf, idxp, pl,
                                                 pacc, cnt_at, out);
}

// Round 12
// 315.149 us; speedup vs baseline: 1.7087x; 1.1606x over previous
//
#include <hip/hip_runtime.h>
#include <math.h>

// Problem constants
#define BB 4
#define TT 4096
#define CC 1024
#define HS 64
#define KSEL 2048
#define NSPL 16   // KV splits per row-block
#define SWLOG 8   // split width = 256
#define SW 256

typedef float f32x4 __attribute__((ext_vector_type(4)));
typedef short short8 __attribute__((ext_vector_type(8)));

__device__ __forceinline__ unsigned short f2bf(float f) {
  union { float f; unsigned int u; } c;
  c.f = f;
  const unsigned int u = c.u;
  return (unsigned short)((u + 0x7FFFu + ((u >> 16) & 1u)) >> 16);  // RTNE
}

// packed f32x2 -> bf16x2 (RTNE), single HW instruction
__device__ __forceinline__ unsigned cvtpk(float lo, float hi) {
  unsigned r;
  asm("v_cvt_pk_bf16_f32 %0, %1, %2" : "=v"(r) : "v"(lo), "v"(hi));
  return r;
}

// ---------------------------------------------------------------------------
// conv_w: Wq|Wk|Wv fp32 -> bf16 B-fragment layout; also zeroes xsum and the
// device-side completion counters (replaces memset dispatches).
// ---------------------------------------------------------------------------
__global__ __launch_bounds__(256) void conv_w(const float* __restrict__ Wq,
                                              const float* __restrict__ Wk,
                                              const float* __restrict__ Wv,
                                              unsigned short* __restrict__ wbf,
                                              float* __restrict__ xsum,
                                              int* __restrict__ cnts) {
  const int gid = blockIdx.x * 256 + threadIdx.x;  // 0..24575
  if (gid < 1024) ((float4*)xsum)[gid] = make_float4(0.f, 0.f, 0.f, 0.f);
  if (gid < 66) ((int4*)cnts)[gid] = make_int4(0, 0, 0, 0);  // 264 ints
  const int kt = gid / 768;
  const int rem = gid - kt * 768;
  const int nt = rem >> 6, lane = rem & 63;
  const int col = nt * 16 + (lane & 15);
  const float* W = (col < 64) ? Wq : ((col < 128) ? Wk : Wv);
  const int cl = col & 63;
  const int k0 = kt * 32 + (lane >> 4) * 8;
  unsigned short tmp[8];
#pragma unroll
  for (int i = 0; i < 8; i++) tmp[i] = f2bf(W[(size_t)(k0 + i) * HS + cl]);
  uint4 o;
  o.x = tmp[0] | ((unsigned)tmp[1] << 16);
  o.y = tmp[2] | ((unsigned)tmp[3] << 16);
  o.z = tmp[4] | ((unsigned)tmp[5] << 16);
  o.w = tmp[6] | ((unsigned)tmp[7] << 16);
  *(uint4*)(wbf + (size_t)gid * 8) = o;
}

// ---------------------------------------------------------------------------
// fusedproj (R6-proven): reads x ONCE. 1024 blocks x 16 rows. Per 256-col
// chunk: stage bf16 into XOR-swizzled LDS, atomicAdd fp32 column sums into
// xsum, MFMA against wbf (L2-hot). Writes q (prescaled 2^-5), k row-major
// bf16, V transposed vt[b][d][t].
// ---------------------------------------------------------------------------
#define PR 16
__global__ __launch_bounds__(256) void fusedproj(
    const float* __restrict__ x, const unsigned short* __restrict__ wbf,
    float* __restrict__ xsum, unsigned short* __restrict__ qbf,
    unsigned short* __restrict__ kbf, unsigned short* __restrict__ vtbf) {
  __shared__ unsigned short Xs[PR][256];  // 8 KB, granule-XOR-swizzled
  __shared__ float xsred[4][256];
  const int rb = blockIdx.x;  // 1024 blocks
  const size_t r0 = (size_t)rb * PR;
  const int tid = threadIdx.x;
  const int wid = tid >> 6, lane = tid & 63;
  const int lhi = lane >> 4, llo = lane & 15;
  const int cl = tid & 63, rg = tid >> 6;
  const int bidx = rb >> 8;

  f32x4 acc[3];
#pragma unroll
  for (int n = 0; n < 3; n++) acc[n] = (f32x4){0.f, 0.f, 0.f, 0.f};

  float4 pf[4];
#pragma unroll
  for (int rr = 0; rr < 4; rr++)
    pf[rr] = *(const float4*)(x + (r0 + rg * 4 + rr) * CC + cl * 4);

  for (int ch = 0; ch < 4; ch++) {
    float ps0 = 0.f, ps1 = 0.f, ps2 = 0.f, ps3 = 0.f;
#pragma unroll
    for (int rr = 0; rr < 4; rr++) {
      const int row = rg * 4 + rr;
      float4 v = pf[rr];
      ps0 += v.x; ps1 += v.y; ps2 += v.z; ps3 += v.w;
      *(uint2*)((char*)&Xs[0][0] + row * 512 +
                ((((cl >> 1) ^ (row & 7))) << 4) + ((cl & 1) << 3)) =
          make_uint2(cvtpk(v.x, v.y), cvtpk(v.z, v.w));
    }
    xsred[rg][cl * 4 + 0] = ps0;
    xsred[rg][cl * 4 + 1] = ps1;
    xsred[rg][cl * 4 + 2] = ps2;
    xsred[rg][cl * 4 + 3] = ps3;
    __syncthreads();
    if (ch < 3) {
#pragma unroll
      for (int rr = 0; rr < 4; rr++)
        pf[rr] = *(const float4*)(x + (r0 + rg * 4 + rr) * CC +
                                  (ch + 1) * 256 + cl * 4);
    }
    atomicAdd(&xsum[bidx * CC + ch * 256 + tid],
              xsred[0][tid] + xsred[1][tid] + xsred[2][tid] + xsred[3][tid]);
#pragma unroll
    for (int ktl = 0; ktl < 8; ktl++) {
      short8 af = *(const short8*)((const char*)&Xs[0][0] + llo * 512 +
                                   ((((ktl << 2) + lhi) ^ (llo & 7)) << 4));
      const unsigned short* bp =
          wbf + (((size_t)(ch * 8 + ktl) * 12 + wid * 3) * 64 + lane) * 8;
#pragma unroll
      for (int n = 0; n < 3; n++) {
        short8 bf = *(const short8*)(bp + n * 64 * 8);
        acc[n] = __builtin_amdgcn_mfma_f32_16x16x32_bf16(af, bf, acc[n], 0, 0, 0);
      }
    }
    __syncthreads();
  }
  const int rbg = (int)r0 + lhi * 4;
#pragma unroll
  for (int n = 0; n < 3; n++) {
    const int col = (wid * 3 + n) * 16 + llo;
    const int mat = col >> 6, cl2 = col & 63;
    if (mat == 0) {
#pragma unroll
      for (int r = 0; r < 4; r++)
        qbf[(size_t)(rbg + r) * HS + cl2] = f2bf(acc[n][r] * 0.03125f);
    } else if (mat == 1) {
#pragma unroll
      for (int r = 0; r < 4; r++)
        kbf[(size_t)(rbg + r) * HS + cl2] = f2bf(acc[n][r]);
    } else {
      const int bb = rbg >> 12, tloc = rbg & (TT - 1);
      *(uint2*)(vtbf + ((size_t)bb * HS + cl2) * TT + tloc) =
          make_uint2(cvtpk(acc[n][0], acc[n][1]), cvtpk(acc[n][2], acc[n][3]));
    }
  }
}

// ---------------------------------------------------------------------------
// rowsums_x (R6-proven): per-block prologue computes w = Wq (Wk^T xsum);
// main: rs[row] = x[row] . w (fp32 exact). 256 blocks x 512 thr.
// ---------------------------------------------------------------------------
__global__ __launch_bounds__(512) void rowsums_x(
    const float* __restrict__ x, const float* __restrict__ Wq,
    const float* __restrict__ Wk, const float* __restrict__ xsum,
    float* __restrict__ rs) {
  __shared__ float xsl[CC];
  __shared__ float kred[8][HS];
  __shared__ float ksl[HS];
  __shared__ float wl[CC];
  const int g = blockIdx.x;
  const int tid = threadIdx.x;
  const int b = g >> 6;
  *(float2*)(xsl + tid * 2) = *(const float2*)(xsum + b * CC + tid * 2);
  __syncthreads();
  {
    const int g8 = tid >> 6, d = tid & 63;
    const float* wkp = Wk + (size_t)(g8 * 128) * HS + d;
    float s = 0.f;
    for (int c = 0; c < 128; c++) s += xsl[g8 * 128 + c] * wkp[(size_t)c * HS];
    kred[g8][d] = s;
  }
  __syncthreads();
  if (tid < 64) {
    float s = 0.f;
#pragma unroll
    for (int g8 = 0; g8 < 8; g8++) s += kred[g8][tid];
    ksl[tid] = s;
  }
  __syncthreads();
#pragma unroll
  for (int p = 0; p < 2; p++) {
    const int c = tid * 2 + p;
    const float* wqp = Wq + (size_t)c * HS;
    float s = 0.f;
#pragma unroll
    for (int d4 = 0; d4 < 16; d4++) {
      float4 a = *(const float4*)(wqp + d4 * 4);
      float4 kk = *(const float4*)(ksl + d4 * 4);
      s += a.x * kk.x + a.y * kk.y + a.z * kk.z + a.w * kk.w;
    }
    wl[c] = s;
  }
  __syncthreads();
  const size_t row = (size_t)g * 64 + (tid >> 3);
  const int qu = tid & 7;
  const float* xr = x + row * CC + qu * 128;
  const float* wr = wl + qu * 128;
  float s = 0.f;
  for (int e = 0; e < 32; e++) {
    float4 v = *(const float4*)(xr + e * 4);
    float4 w4 = *(const float4*)(wr + e * 4);
    s += v.x * w4.x + v.y * w4.y + v.z * w4.z + v.w * w4.w;
  }
  s += __shfl_xor(s, 1);
  s += __shfl_xor(s, 2);
  s += __shfl_xor(s, 4);
  if (qu == 0) rs[row] = s;
}

// ---------------------------------------------------------------------------
// rankk_compact (R11-proven): rank (512 blocks), last block per batch
// compacts flags -> ascending idx in its tail.
// ---------------------------------------------------------------------------
__global__ __launch_bounds__(256) void rankk_compact(
    const float* __restrict__ rs, int* __restrict__ flag,
    int* __restrict__ idxp, int* __restrict__ cnt_rk) {
  __shared__ float rl[TT];
  __shared__ int lastFlag;
  const int g = blockIdx.x;  // B*128
  const int b = g >> 7, chunk = g & 127;
  const int tid = threadIdx.x;
  const int wid = tid >> 6, lane = tid & 63;
  const float* rsb = rs + (size_t)b * TT;
  for (int e = tid; e < TT / 4; e += 256)
    *(float4*)(rl + e * 4) = *(const float4*)(rsb + e * 4);
  __syncthreads();
  {
    const int cand = tid >> 3, qu = tid & 7;
    const int t = chunk * 32 + cand;
    const float my = rl[t];
    int cnt = 0;
    for (int e = 0; e < 128; e++) {
      const int s = qu * 512 + e * 4;
      float4 v = *(const float4*)(rl + s);
      cnt += (v.x > my) || (v.x == my && (s + 0) < t);
      cnt += (v.y > my) || (v.y == my && (s + 1) < t);
      cnt += (v.z > my) || (v.z == my && (s + 2) < t);
      cnt += (v.w > my) || (v.w == my && (s + 3) < t);
    }
    cnt += __shfl_xor(cnt, 1);
    cnt += __shfl_xor(cnt, 2);
    cnt += __shfl_xor(cnt, 4);
    if (qu == 0) flag[(size_t)b * TT + t] = (cnt < KSEL) ? 1 : 0;
  }
  __threadfence();  // release flags
  __syncthreads();
  if (tid == 0) lastFlag = (atomicAdd(&cnt_rk[b], 1) == 127);
  __syncthreads();
  if (!lastFlag) return;
  __threadfence();  // acquire all batch flags
  __shared__ int wsum[4];
  __shared__ int woff[4];
  const int* fb = flag + (size_t)b * TT;
  const int base = tid * 16;
  int f[16];
  int cnt = 0;
#pragma unroll
  for (int e4 = 0; e4 < 4; e4++) {
    int4 v = *(const int4*)(fb + base + e4 * 4);
    f[e4 * 4 + 0] = v.x; f[e4 * 4 + 1] = v.y;
    f[e4 * 4 + 2] = v.z; f[e4 * 4 + 3] = v.w;
    cnt += v.x + v.y + v.z + v.w;
  }
  int sc = cnt;
#pragma unroll
  for (int d = 1; d < 64; d <<= 1) {
    int v = __shfl_up(sc, d);
    if (lane >= d) sc += v;
  }
  if (lane == 63) wsum[wid] = sc;
  __syncthreads();
  if (tid == 0) {
    int a = 0;
#pragma unroll
    for (int w = 0; w < 4; w++) { woff[w] = a; a += wsum[w]; }
  }
  __syncthreads();
  int pos = woff[wid] + sc - cnt;
#pragma unroll
  for (int e = 0; e < 16; e++)
    if (f[e]) idxp[(size_t)b * KSEL + (pos++)] = base + e;
}

// ---------------------------------------------------------------------------
// attn_mfma + BLOCK-LEVEL fused combine. Compute is the R6-proven inner
// loop (swapped QK^T, no-max softmax, split-j). No early return: inactive
// waves skip compute and join the block barrier. Each of the 4 zz-blocks
// per (b,rb) bumps a counter; the 4th runs the combine with ALL 256
// threads (thread = (row, dim-group) -- same parallelism as the old
// dedicated combine kernel, R11's serial 1-wave tail was the regression).
// ---------------------------------------------------------------------------
struct KF { short8 a0, a1, b0, b1; };
struct VF { short8 v0, v1, v2, v3; };

__global__ __launch_bounds__(256) void attn_mfma(
    const unsigned short* __restrict__ qbf,
    const unsigned short* __restrict__ kbf,
    const unsigned short* __restrict__ vtbf, const int* __restrict__ idx,
    float* __restrict__ pl, float* __restrict__ pacc,
    int* __restrict__ cnt_at, float* __restrict__ out) {
  __shared__ unsigned short P_lds[4][32][40];
  __shared__ int lastArr;
  const int rb = blockIdx.x;
  const int zz = blockIdx.y;
  const int b = blockIdx.z;
  const int tid = threadIdx.x;
  const int wid = tid >> 6, lane = tid & 63;
  const int s = zz * 4 + wid;  // split 0..15
  const size_t rbase = (size_t)b * KSEL + rb * 32;
  const int tmaxblk = idx[rbase + 31];
  const int jlo = s << SWLOG;
  const bool active = (jlo <= tmaxblk);

  const int lhi = lane >> 4, llo = lane & 15;
  if (active) {
    const int trow0 = idx[rbase + llo];
    const int trow1 = idx[rbase + 16 + llo];
    short8 qf[2][2];
    {
      const unsigned short* qp0 = qbf + ((size_t)b * TT + trow0) * HS + lhi * 8;
      const unsigned short* qp1 = qbf + ((size_t)b * TT + trow1) * HS + lhi * 8;
      qf[0][0] = *(const short8*)(qp0);
      qf[0][1] = *(const short8*)(qp0 + 32);
      qf[1][0] = *(const short8*)(qp1);
      qf[1][1] = *(const short8*)(qp1 + 32);
    }
    f32x4 o[2][4];
#pragma unroll
    for (int mtt = 0; mtt < 2; mtt++)
#pragma unroll
      for (int n = 0; n < 4; n++) o[mtt][n] = (f32x4){0.f, 0.f, 0.f, 0.f};
    float lsum[2] = {0.f, 0.f};

    const unsigned short* kb = kbf + (size_t)b * TT * HS;
    const unsigned short* vb = vtbf + (size_t)b * HS * TT;
    const int jend = min(tmaxblk + 1, jlo + SW);

    auto loadK = [&](int j0) {
      KF K;
      const unsigned short* kp = kb + (size_t)(j0 + llo) * HS + lhi * 8;
      K.a0 = *(const short8*)(kp);
      K.a1 = *(const short8*)(kp + 32);
      K.b0 = *(const short8*)(kp + 16 * HS);
      K.b1 = *(const short8*)(kp + 16 * HS + 32);
      return K;
    };
    auto loadV = [&](int j0) {
      VF V;
      const unsigned short* vp = vb + (size_t)llo * TT + j0 + lhi * 8;
      V.v0 = *(const short8*)(vp);
      V.v1 = *(const short8*)(vp + 16 * TT);
      V.v2 = *(const short8*)(vp + 32 * TT);
      V.v3 = *(const short8*)(vp + 48 * TT);
      return V;
    };

    auto body = [&](int j0, const KF& K, const VF& V) {
      f32x4 sc[2][2];
#pragma unroll
      for (int mtt = 0; mtt < 2; mtt++) {
        f32x4 a = (f32x4){0.f, 0.f, 0.f, 0.f};
        a = __builtin_amdgcn_mfma_f32_16x16x32_bf16(K.a0, qf[mtt][0], a, 0, 0, 0);
        a = __builtin_amdgcn_mfma_f32_16x16x32_bf16(K.a1, qf[mtt][1], a, 0, 0, 0);
        sc[mtt][0] = a;
        f32x4 c = (f32x4){0.f, 0.f, 0.f, 0.f};
        c = __builtin_amdgcn_mfma_f32_16x16x32_bf16(K.b0, qf[mtt][0], c, 0, 0, 0);
        c = __builtin_amdgcn_mfma_f32_16x16x32_bf16(K.b1, qf[mtt][1], c, 0, 0, 0);
        sc[mtt][1] = c;
      }
#pragma unroll
      for (int mtt = 0; mtt < 2; mtt++) {
        const int tr = (mtt == 0) ? trow0 : trow1;
        float p[8];
#pragma unroll
        for (int kt = 0; kt < 2; kt++)
#pragma unroll
          for (int r = 0; r < 4; r++) {
            const int kk = j0 + kt * 16 + lhi * 4 + r;
            const float e = __expf(sc[mtt][kt][r]);
            p[kt * 4 + r] = (kk <= tr) ? e : 0.f;
          }
        lsum[mtt] += ((p[0] + p[1]) + (p[2] + p[3])) +
                     ((p[4] + p[5]) + (p[6] + p[7]));
        *(uint2*)&P_lds[wid][mtt * 16 + llo][lhi * 4] =
            make_uint2(cvtpk(p[0], p[1]), cvtpk(p[2], p[3]));
        *(uint2*)&P_lds[wid][mtt * 16 + llo][16 + lhi * 4] =
            make_uint2(cvtpk(p[4], p[5]), cvtpk(p[6], p[7]));
      }
      short8 pa0 = *(const short8*)&P_lds[wid][llo][lhi * 8];
      short8 pa1 = *(const short8*)&P_lds[wid][16 + llo][lhi * 8];
      o[0][0] = __builtin_amdgcn_mfma_f32_16x16x32_bf16(pa0, V.v0, o[0][0], 0, 0, 0);
      o[1][0] = __builtin_amdgcn_mfma_f32_16x16x32_bf16(pa1, V.v0, o[1][0], 0, 0, 0);
      o[0][1] = __builtin_amdgcn_mfma_f32_16x16x32_bf16(pa0, V.v1, o[0][1], 0, 0, 0);
      o[1][1] = __builtin_amdgcn_mfma_f32_16x16x32_bf16(pa1, V.v1, o[1][1], 0, 0, 0);
      o[0][2] = __builtin_amdgcn_mfma_f32_16x16x32_bf16(pa0, V.v2, o[0][2], 0, 0, 0);
      o[1][2] = __builtin_amdgcn_mfma_f32_16x16x32_bf16(pa1, V.v2, o[1][2], 0, 0, 0);
      o[0][3] = __builtin_amdgcn_mfma_f32_16x16x32_bf16(pa0, V.v3, o[0][3], 0, 0, 0);
      o[1][3] = __builtin_amdgcn_mfma_f32_16x16x32_bf16(pa1, V.v3, o[1][3], 0, 0, 0);
    };

    int j0 = jlo;
    KF ka = loadK(j0), kb2;
    VF va = loadV(j0), vb2;
    for (;;) {
      if (j0 + 32 < jend) { kb2 = loadK(j0 + 32); vb2 = loadV(j0 + 32); }
      body(j0, ka, va);
      j0 += 32;
      if (j0 >= jend) break;
      if (j0 + 32 < jend) { ka = loadK(j0 + 32); va = loadV(j0 + 32); }
      body(j0, kb2, vb2);
      j0 += 32;
      if (j0 >= jend) break;
    }

    lsum[0] += __shfl_xor(lsum[0], 16);
    lsum[0] += __shfl_xor(lsum[0], 32);
    lsum[1] += __shfl_xor(lsum[1], 16);
    lsum[1] += __shfl_xor(lsum[1], 32);
    if (lane < 16) {
      pl[(rbase + llo) * NSPL + s] = lsum[0];
      pl[(rbase + 16 + llo) * NSPL + s] = lsum[1];
    }
#pragma unroll
    for (int mtt = 0; mtt < 2; mtt++)
#pragma unroll
      for (int r = 0; r < 4; r++) {
        const size_t rowi = rbase + mtt * 16 + lhi * 4 + r;
#pragma unroll
        for (int n = 0; n < 4; n++)
          pacc[(rowi * NSPL + s) * HS + n * 16 + llo] = o[mtt][n][r];
      }
  }

  // ---- block-level fused combine ----
  __threadfence();  // release this block's partials
  __syncthreads();
  if (tid == 0) lastArr = (atomicAdd(&cnt_at[b * 64 + rb], 1) == 3);
  __syncthreads();
  if (!lastArr) return;
  __threadfence();  // acquire all 4 blocks' partials
  {
    const int r = tid >> 3, dg = tid & 7;  // 32 rows x 8 dim-groups
    const size_t rowi = rbase + r;
    const int nsr = (idx[rowi] >> SWLOG) + 1;
    float L = 0.f;
    float o0 = 0.f, o1 = 0.f, o2 = 0.f, o3 = 0.f;
    float o4 = 0.f, o5 = 0.f, o6 = 0.f, o7 = 0.f;
    for (int ss = 0; ss < nsr; ss++) {
      L += pl[rowi * NSPL + ss];
      const float* pa = pacc + (rowi * NSPL + ss) * HS + dg * 8;
      float4 a0 = *(const float4*)(pa);
      float4 a1 = *(const float4*)(pa + 4);
      o0 += a0.x; o1 += a0.y; o2 += a0.z; o3 += a0.w;
      o4 += a1.x; o5 += a1.y; o6 += a1.z; o7 += a1.w;
    }
    const float invl = 1.0f / L;
    float* op = out + rowi * HS + dg * 8;
    *(float4*)(op) = make_float4(o0 * invl, o1 * invl, o2 * invl, o3 * invl);
    *(float4*)(op + 4) =
        make_float4(o4 * invl, o5 * invl, o6 * invl, o7 * invl);
  }
}

// ---------------------------------------------------------------------------
extern "C" void kernel_launch(void* const* d_in, const int* in_sizes, int n_in,
                              void* d_out, int out_size, void* d_ws,
                              size_t ws_size, hipStream_t stream) {
  const float* x = (const float*)d_in[0];
  const float* Wq = (const float*)d_in[1];
  const float* Wk = (const float*)d_in[2];
  const float* Wv = (const float*)d_in[3];
  float* out = (float*)d_out;

  float* wsf = (float*)d_ws;
  // pacc (attn phase) overlaps selection-phase scratch (dead by then).
  float* pacc = wsf;                                      // 8,388,608 f
  float* xsum = wsf;                                      // 4,096 f
  float* rs = xsum + 4096;                                // 16,384 f
  int* flag = (int*)(rs + 16384);                         // 16,384 i
  unsigned short* wbf = (unsigned short*)(flag + 16384);  // 196,608 us
  // Live through attn:
  unsigned short* qbf = (unsigned short*)(pacc + 8388608);  // 1,048,576 us
  unsigned short* kbf = qbf + 1048576;                      // 1,048,576 us
  unsigned short* vtbf = kbf + 1048576;                     // 1,048,576 us
  int* idxp = (int*)(vtbf + 1048576);                       // 8,192 i
  float* pl = (float*)(idxp + 8192);                        // 131,072 f
  int* cnts = (int*)(pl + 131072);  // 264 i: [0..3]=rank, [8..263]=attn
  int* cnt_rk = cnts;
  int* cnt_at = cnts + 8;

  conv_w<<<96, 256, 0, stream>>>(Wq, Wk, Wv, wbf, xsum, cnts);
  fusedproj<<<1024, 256, 0, stream>>>(x, wbf, xsum, qbf, kbf, vtbf);
  rowsums_x<<<256, 512, 0, stream>>>(x, Wq, Wk, xsum, rs);
  rankk_compact<<<512, 256, 0, stream>>>(rs, flag, idxp, cnt_rk);
  attn_mfma<<<dim3(64, 4, BB), 256, 0, stream>>>(qbf, kbf, vtbf, idxp, pl,
                                                 pacc, cnt_at, out);
}

// Round 13
// 125.278 us; speedup vs baseline: 4.2984x; 2.5156x over previous
//
#include <hip/hip_runtime.h>
#include <math.h>

// Problem constants
#define BB 4
#define TT 4096
#define CC 1024
#define HS 64
#define KSEL 2048
#define NSPL 16   // KV splits per row-block
#define SWLOG 8   // split width = 256
#define SW 256

typedef float f32x4 __attribute__((ext_vector_type(4)));
typedef short short8 __attribute__((ext_vector_type(8)));

__device__ __forceinline__ unsigned short f2bf(float f) {
  union { float f; unsigned int u; } c;
  c.f = f;
  const unsigned int u = c.u;
  return (unsigned short)((u + 0x7FFFu + ((u >> 16) & 1u)) >> 16);  // RTNE
}

// packed f32x2 -> bf16x2 (RTNE), single HW instruction
__device__ __forceinline__ unsigned cvtpk(float lo, float hi) {
  unsigned r;
  asm("v_cvt_pk_bf16_f32 %0, %1, %2" : "=v"(r) : "v"(lo), "v"(hi));
  return r;
}

// ---------------------------------------------------------------------------
// conv_w: Wq|Wk|Wv fp32 -> bf16 B-fragment layout; also zeroes xsum (the
// only accumulator) -- kernel-boundary ordering makes this safe, no fence.
// ---------------------------------------------------------------------------
__global__ __launch_bounds__(256) void conv_w(const float* __restrict__ Wq,
                                              const float* __restrict__ Wk,
                                              const float* __restrict__ Wv,
                                              unsigned short* __restrict__ wbf,
                                              float* __restrict__ xsum) {
  const int gid = blockIdx.x * 256 + threadIdx.x;  // 0..24575
  if (gid < 1024) ((float4*)xsum)[gid] = make_float4(0.f, 0.f, 0.f, 0.f);
  const int kt = gid / 768;
  const int rem = gid - kt * 768;
  const int nt = rem >> 6, lane = rem & 63;
  const int col = nt * 16 + (lane & 15);
  const float* W = (col < 64) ? Wq : ((col < 128) ? Wk : Wv);
  const int cl = col & 63;
  const int k0 = kt * 32 + (lane >> 4) * 8;
  unsigned short tmp[8];
#pragma unroll
  for (int i = 0; i < 8; i++) tmp[i] = f2bf(W[(size_t)(k0 + i) * HS + cl]);
  uint4 o;
  o.x = tmp[0] | ((unsigned)tmp[1] << 16);
  o.y = tmp[2] | ((unsigned)tmp[3] << 16);
  o.z = tmp[4] | ((unsigned)tmp[5] << 16);
  o.w = tmp[6] | ((unsigned)tmp[7] << 16);
  *(uint4*)(wbf + (size_t)gid * 8) = o;
}

// ---------------------------------------------------------------------------
// fusedproj (exact R6/128.6us version): reads x ONCE. 512 blocks x 32 rows.
// Per 256-col chunk: stage bf16 into XOR-swizzled LDS, atomicAdd fp32 column
// sums into xsum, MFMA against wbf (L2-hot). Writes q (prescaled 2^-5), k
// row-major bf16, V transposed vt[b][d][t].
// ---------------------------------------------------------------------------
#define PR 32
__global__ __launch_bounds__(256) void fusedproj(
    const float* __restrict__ x, const unsigned short* __restrict__ wbf,
    float* __restrict__ xsum, unsigned short* __restrict__ qbf,
    unsigned short* __restrict__ kbf, unsigned short* __restrict__ vtbf) {
  __shared__ unsigned short Xs[PR][256];  // 16 KB, granule-XOR-swizzled
  __shared__ float xsred[4][256];
  const int rb = blockIdx.x;  // 512 blocks
  const size_t r0 = (size_t)rb * PR;
  const int tid = threadIdx.x;
  const int wid = tid >> 6, lane = tid & 63;
  const int lhi = lane >> 4, llo = lane & 15;
  const int mt = wid >> 1, nh = wid & 1;
  const int cl = tid & 63, rg = tid >> 6;
  const int bidx = rb >> 7;

  f32x4 acc[6];
#pragma unroll
  for (int n = 0; n < 6; n++) acc[n] = (f32x4){0.f, 0.f, 0.f, 0.f};

  float4 pf[8];
#pragma unroll
  for (int rr = 0; rr < 8; rr++)
    pf[rr] = *(const float4*)(x + (r0 + rg * 8 + rr) * CC + cl * 4);

  for (int ch = 0; ch < 4; ch++) {
    float ps0 = 0.f, ps1 = 0.f, ps2 = 0.f, ps3 = 0.f;
#pragma unroll
    for (int rr = 0; rr < 8; rr++) {
      const int row = rg * 8 + rr;
      float4 v = pf[rr];
      ps0 += v.x; ps1 += v.y; ps2 += v.z; ps3 += v.w;
      *(uint2*)((char*)&Xs[0][0] + row * 512 +
                ((((cl >> 1) ^ (row & 7))) << 4) + ((cl & 1) << 3)) =
          make_uint2(cvtpk(v.x, v.y), cvtpk(v.z, v.w));
    }
    xsred[rg][cl * 4 + 0] = ps0;
    xsred[rg][cl * 4 + 1] = ps1;
    xsred[rg][cl * 4 + 2] = ps2;
    xsred[rg][cl * 4 + 3] = ps3;
    __syncthreads();
    // issue next-chunk prefetch NOW; latency hides under atomic + MFMA
    if (ch < 3) {
#pragma unroll
      for (int rr = 0; rr < 8; rr++)
        pf[rr] = *(const float4*)(x + (r0 + rg * 8 + rr) * CC +
                                  (ch + 1) * 256 + cl * 4);
    }
    atomicAdd(&xsum[bidx * CC + ch * 256 + tid],
              xsred[0][tid] + xsred[1][tid] + xsred[2][tid] + xsred[3][tid]);
    const int row = mt * 16 + llo;
#pragma unroll
    for (int ktl = 0; ktl < 8; ktl++) {
      short8 af = *(const short8*)((const char*)&Xs[0][0] + row * 512 +
                                   ((((ktl << 2) + lhi) ^ (row & 7)) << 4));
      const unsigned short* bp =
          wbf + (((size_t)(ch * 8 + ktl) * 12 + nh * 6) * 64 + lane) * 8;
#pragma unroll
      for (int n = 0; n < 6; n++) {
        short8 bf = *(const short8*)(bp + n * 64 * 8);
        acc[n] = __builtin_amdgcn_mfma_f32_16x16x32_bf16(af, bf, acc[n], 0, 0, 0);
      }
    }
    __syncthreads();
  }
  const int rbg = (int)r0 + mt * 16 + lhi * 4;
#pragma unroll
  for (int n = 0; n < 6; n++) {
    const int col = (nh * 6 + n) * 16 + llo;
    const int mat = col >> 6, cl2 = col & 63;
    if (mat == 0) {
#pragma unroll
      for (int r = 0; r < 4; r++)
        qbf[(size_t)(rbg + r) * HS + cl2] = f2bf(acc[n][r] * 0.03125f);
    } else if (mat == 1) {
#pragma unroll
      for (int r = 0; r < 4; r++)
        kbf[(size_t)(rbg + r) * HS + cl2] = f2bf(acc[n][r]);
    } else {
      const int bb = rbg >> 12, tloc = rbg & (TT - 1);
      *(uint2*)(vtbf + ((size_t)bb * HS + cl2) * TT + tloc) =
          make_uint2(cvtpk(acc[n][0], acc[n][1]), cvtpk(acc[n][2], acc[n][3]));
    }
  }
}

// ---------------------------------------------------------------------------
// rowsums_x (R6-proven): per-block prologue computes w = Wq (Wk^T xsum);
// main: rs[row] = x[row] . w (fp32 exact for selection). 256 blocks x 512.
// ---------------------------------------------------------------------------
__global__ __launch_bounds__(512) void rowsums_x(
    const float* __restrict__ x, const float* __restrict__ Wq,
    const float* __restrict__ Wk, const float* __restrict__ xsum,
    float* __restrict__ rs) {
  __shared__ float xsl[CC];
  __shared__ float kred[8][HS];
  __shared__ float ksl[HS];
  __shared__ float wl[CC];
  const int g = blockIdx.x;
  const int tid = threadIdx.x;
  const int b = g >> 6;
  *(float2*)(xsl + tid * 2) = *(const float2*)(xsum + b * CC + tid * 2);
  __syncthreads();
  {
    const int g8 = tid >> 6, d = tid & 63;
    const float* wkp = Wk + (size_t)(g8 * 128) * HS + d;
    float s = 0.f;
    for (int c = 0; c < 128; c++) s += xsl[g8 * 128 + c] * wkp[(size_t)c * HS];
    kred[g8][d] = s;
  }
  __syncthreads();
  if (tid < 64) {
    float s = 0.f;
#pragma unroll
    for (int g8 = 0; g8 < 8; g8++) s += kred[g8][tid];
    ksl[tid] = s;
  }
  __syncthreads();
#pragma unroll
  for (int p = 0; p < 2; p++) {
    const int c = tid * 2 + p;
    const float* wqp = Wq + (size_t)c * HS;
    float s = 0.f;
#pragma unroll
    for (int d4 = 0; d4 < 16; d4++) {
      float4 a = *(const float4*)(wqp + d4 * 4);
      float4 kk = *(const float4*)(ksl + d4 * 4);
      s += a.x * kk.x + a.y * kk.y + a.z * kk.z + a.w * kk.w;
    }
    wl[c] = s;
  }
  __syncthreads();
  const size_t row = (size_t)g * 64 + (tid >> 3);
  const int qu = tid & 7;
  const float* xr = x + row * CC + qu * 128;
  const float* wr = wl + qu * 128;
  float s = 0.f;
  for (int e = 0; e < 32; e++) {
    float4 v = *(const float4*)(xr + e * 4);
    float4 w4 = *(const float4*)(wr + e * 4);
    s += v.x * w4.x + v.y * w4.y + v.z * w4.z + v.w * w4.w;
  }
  s += __shfl_xor(s, 1);
  s += __shfl_xor(s, 2);
  s += __shfl_xor(s, 4);
  if (qu == 0) rs[row] = s;
}

// ---------------------------------------------------------------------------
// rankk (R6-proven): flag[t] = t in top-2048 (ties: lower index). 512 blocks.
// ---------------------------------------------------------------------------
__global__ __launch_bounds__(256) void rankk(const float* __restrict__ rs,
                                             int* __restrict__ flag) {
  __shared__ float rl[TT];
  const int g = blockIdx.x;  // B*128
  const int b = g >> 7, chunk = g & 127;
  const int tid = threadIdx.x;
  const float* rsb = rs + (size_t)b * TT;
  for (int e = tid; e < TT / 4; e += 256)
    *(float4*)(rl + e * 4) = *(const float4*)(rsb + e * 4);
  __syncthreads();
  const int cand = tid >> 3, qu = tid & 7;
  const int t = chunk * 32 + cand;
  const float my = rl[t];
  int cnt = 0;
  for (int e = 0; e < 128; e++) {
    const int s = qu * 512 + e * 4;
    float4 v = *(const float4*)(rl + s);
    cnt += (v.x > my) || (v.x == my && (s + 0) < t);
    cnt += (v.y > my) || (v.y == my && (s + 1) < t);
    cnt += (v.z > my) || (v.z == my && (s + 2) < t);
    cnt += (v.w > my) || (v.w == my && (s + 3) < t);
  }
  cnt += __shfl_xor(cnt, 1);
  cnt += __shfl_xor(cnt, 2);
  cnt += __shfl_xor(cnt, 4);
  if (qu == 0) flag[(size_t)b * TT + t] = (cnt < KSEL) ? 1 : 0;
}

// ---------------------------------------------------------------------------
// compact (R8-proven wave-scan): flags -> ascending idx. 4 blocks.
// ---------------------------------------------------------------------------
__global__ __launch_bounds__(256) void compact(const int* __restrict__ flag,
                                               int* __restrict__ idx) {
  __shared__ int wsum[4];
  __shared__ int woff[4];
  const int b = blockIdx.x;
  const int tid = threadIdx.x;
  const int wid = tid >> 6, lane = tid & 63;
  const int* fb = flag + (size_t)b * TT;
  const int base = tid * 16;
  int f[16];
  int cnt = 0;
#pragma unroll
  for (int e4 = 0; e4 < 4; e4++) {
    int4 v = *(const int4*)(fb + base + e4 * 4);
    f[e4 * 4 + 0] = v.x; f[e4 * 4 + 1] = v.y;
    f[e4 * 4 + 2] = v.z; f[e4 * 4 + 3] = v.w;
    cnt += v.x + v.y + v.z + v.w;
  }
  int sc = cnt;
#pragma unroll
  for (int d = 1; d < 64; d <<= 1) {
    int v = __shfl_up(sc, d);
    if (lane >= d) sc += v;
  }
  if (lane == 63) wsum[wid] = sc;
  __syncthreads();
  if (tid == 0) {
    int a = 0;
#pragma unroll
    for (int w = 0; w < 4; w++) { woff[w] = a; a += wsum[w]; }
  }
  __syncthreads();
  int pos = woff[wid] + sc - cnt;
#pragma unroll
  for (int e = 0; e < 16; e++)
    if (f[e]) idx[(size_t)b * KSEL + (pos++)] = base + e;
}

// ---------------------------------------------------------------------------
// attn_mfma (exact R6/128.6us version): swapped-operand QK^T + no-max
// softmax (scores bounded by construction; scale folded into q). No
// cross-lane ops in the loop; streaming pl/pacc partial writes, NO fences.
// grid (rb=64, zz=4, b=4); wave = one KV split (NS=16, width 256).
// ---------------------------------------------------------------------------
struct KF { short8 a0, a1, b0, b1; };
struct VF { short8 v0, v1, v2, v3; };

__global__ __launch_bounds__(256) void attn_mfma(
    const unsigned short* __restrict__ qbf,
    const unsigned short* __restrict__ kbf,
    const unsigned short* __restrict__ vtbf, const int* __restrict__ idx,
    float* __restrict__ pl, float* __restrict__ pacc) {
  __shared__ unsigned short P_lds[4][32][40];
  const int rb = blockIdx.x;
  const int zz = blockIdx.y;
  const int b = blockIdx.z;
  const int tid = threadIdx.x;
  const int wid = tid >> 6, lane = tid & 63;
  const int s = zz * 4 + wid;  // split 0..15
  const size_t rbase = (size_t)b * KSEL + rb * 32;
  const int tmaxblk = idx[rbase + 31];
  const int jlo = s << SWLOG;
  if (jlo > tmaxblk) return;

  const int lhi = lane >> 4, llo = lane & 15;
  const int trow0 = idx[rbase + llo];
  const int trow1 = idx[rbase + 16 + llo];
  short8 qf[2][2];
  {
    const unsigned short* qp0 = qbf + ((size_t)b * TT + trow0) * HS + lhi * 8;
    const unsigned short* qp1 = qbf + ((size_t)b * TT + trow1) * HS + lhi * 8;
    qf[0][0] = *(const short8*)(qp0);
    qf[0][1] = *(const short8*)(qp0 + 32);
    qf[1][0] = *(const short8*)(qp1);
    qf[1][1] = *(const short8*)(qp1 + 32);
  }
  f32x4 o[2][4];
#pragma unroll
  for (int mtt = 0; mtt < 2; mtt++)
#pragma unroll
    for (int n = 0; n < 4; n++) o[mtt][n] = (f32x4){0.f, 0.f, 0.f, 0.f};
  float lsum[2] = {0.f, 0.f};

  const unsigned short* kb = kbf + (size_t)b * TT * HS;
  const unsigned short* vb = vtbf + (size_t)b * HS * TT;
  const int jend = min(tmaxblk + 1, jlo + SW);

  auto loadK = [&](int j0) {
    KF K;
    const unsigned short* kp = kb + (size_t)(j0 + llo) * HS + lhi * 8;
    K.a0 = *(const short8*)(kp);
    K.a1 = *(const short8*)(kp + 32);
    K.b0 = *(const short8*)(kp + 16 * HS);
    K.b1 = *(const short8*)(kp + 16 * HS + 32);
    return K;
  };
  auto loadV = [&](int j0) {
    VF V;
    const unsigned short* vp = vb + (size_t)llo * TT + j0 + lhi * 8;
    V.v0 = *(const short8*)(vp);
    V.v1 = *(const short8*)(vp + 16 * TT);
    V.v2 = *(const short8*)(vp + 32 * TT);
    V.v3 = *(const short8*)(vp + 48 * TT);
    return V;
  };

  auto body = [&](int j0, const KF& K, const VF& V) {
    f32x4 sc[2][2];
#pragma unroll
    for (int mtt = 0; mtt < 2; mtt++) {
      f32x4 a = (f32x4){0.f, 0.f, 0.f, 0.f};
      a = __builtin_amdgcn_mfma_f32_16x16x32_bf16(K.a0, qf[mtt][0], a, 0, 0, 0);
      a = __builtin_amdgcn_mfma_f32_16x16x32_bf16(K.a1, qf[mtt][1], a, 0, 0, 0);
      sc[mtt][0] = a;
      f32x4 c = (f32x4){0.f, 0.f, 0.f, 0.f};
      c = __builtin_amdgcn_mfma_f32_16x16x32_bf16(K.b0, qf[mtt][0], c, 0, 0, 0);
      c = __builtin_amdgcn_mfma_f32_16x16x32_bf16(K.b1, qf[mtt][1], c, 0, 0, 0);
      sc[mtt][1] = c;
    }
#pragma unroll
    for (int mtt = 0; mtt < 2; mtt++) {
      const int tr = (mtt == 0) ? trow0 : trow1;
      float p[8];
#pragma unroll
      for (int kt = 0; kt < 2; kt++)
#pragma unroll
        for (int r = 0; r < 4; r++) {
          const int kk = j0 + kt * 16 + lhi * 4 + r;
          const float e = __expf(sc[mtt][kt][r]);
          p[kt * 4 + r] = (kk <= tr) ? e : 0.f;
        }
      lsum[mtt] += ((p[0] + p[1]) + (p[2] + p[3])) +
                   ((p[4] + p[5]) + (p[6] + p[7]));
      *(uint2*)&P_lds[wid][mtt * 16 + llo][lhi * 4] =
          make_uint2(cvtpk(p[0], p[1]), cvtpk(p[2], p[3]));
      *(uint2*)&P_lds[wid][mtt * 16 + llo][16 + lhi * 4] =
          make_uint2(cvtpk(p[4], p[5]), cvtpk(p[6], p[7]));
    }
    // PV (same-wave DS ordering -> no barrier needed)
    short8 pa0 = *(const short8*)&P_lds[wid][llo][lhi * 8];
    short8 pa1 = *(const short8*)&P_lds[wid][16 + llo][lhi * 8];
    o[0][0] = __builtin_amdgcn_mfma_f32_16x16x32_bf16(pa0, V.v0, o[0][0], 0, 0, 0);
    o[1][0] = __builtin_amdgcn_mfma_f32_16x16x32_bf16(pa1, V.v0, o[1][0], 0, 0, 0);
    o[0][1] = __builtin_amdgcn_mfma_f32_16x16x32_bf16(pa0, V.v1, o[0][1], 0, 0, 0);
    o[1][1] = __builtin_amdgcn_mfma_f32_16x16x32_bf16(pa1, V.v1, o[1][1], 0, 0, 0);
    o[0][2] = __builtin_amdgcn_mfma_f32_16x16x32_bf16(pa0, V.v2, o[0][2], 0, 0, 0);
    o[1][2] = __builtin_amdgcn_mfma_f32_16x16x32_bf16(pa1, V.v2, o[1][2], 0, 0, 0);
    o[0][3] = __builtin_amdgcn_mfma_f32_16x16x32_bf16(pa0, V.v3, o[0][3], 0, 0, 0);
    o[1][3] = __builtin_amdgcn_mfma_f32_16x16x32_bf16(pa1, V.v3, o[1][3], 0, 0, 0);
  };

  int j0 = jlo;
  KF ka = loadK(j0), kb2;
  VF va = loadV(j0), vb2;
  for (;;) {
    if (j0 + 32 < jend) { kb2 = loadK(j0 + 32); vb2 = loadV(j0 + 32); }
    body(j0, ka, va);
    j0 += 32;
    if (j0 >= jend) break;
    if (j0 + 32 < jend) { ka = loadK(j0 + 32); va = loadV(j0 + 32); }
    body(j0, kb2, vb2);
    j0 += 32;
    if (j0 >= jend) break;
  }

  // epilogue: streaming partial writes (combine is a plain sum)
  lsum[0] += __shfl_xor(lsum[0], 16);
  lsum[0] += __shfl_xor(lsum[0], 32);
  lsum[1] += __shfl_xor(lsum[1], 16);
  lsum[1] += __shfl_xor(lsum[1], 32);
  if (lane < 16) {
    pl[(rbase + llo) * NSPL + s] = lsum[0];
    pl[(rbase + 16 + llo) * NSPL + s] = lsum[1];
  }
#pragma unroll
  for (int mtt = 0; mtt < 2; mtt++)
#pragma unroll
    for (int r = 0; r < 4; r++) {
      const size_t rowi = rbase + mtt * 16 + lhi * 4 + r;
#pragma unroll
      for (int n = 0; n < 4; n++)
        pacc[(rowi * NSPL + s) * HS + n * 16 + llo] = o[mtt][n][r];
    }
}

// ---------------------------------------------------------------------------
// attn_combine (R6-proven): plain sums over active splits, then normalize.
// ---------------------------------------------------------------------------
__global__ __launch_bounds__(256) void attn_combine(
    const float* __restrict__ pl, const float* __restrict__ pacc,
    const int* __restrict__ idx, float* __restrict__ out) {
  const int b = blockIdx.x;
  const int i0 = blockIdx.y * 32;
  const int tid = threadIdx.x;
  const int r = tid >> 3, dg = tid & 7;
  const size_t rowi = (size_t)b * KSEL + i0 + r;
  const int t_r = idx[rowi];
  const int ns = (t_r >> SWLOG) + 1;
  float L = 0.f;
  float o[8] = {0.f, 0.f, 0.f, 0.f, 0.f, 0.f, 0.f, 0.f};
  for (int s = 0; s < ns; s++) {
    L += pl[rowi * NSPL + s];
    const float* pa = pacc + (rowi * NSPL + s) * HS + dg * 8;
    float4 a0 = *(const float4*)(pa);
    float4 a1 = *(const float4*)(pa + 4);
    o[0] += a0.x; o[1] += a0.y; o[2] += a0.z; o[3] += a0.w;
    o[4] += a1.x; o[5] += a1.y; o[6] += a1.z; o[7] += a1.w;
  }
  const float invl = 1.0f / L;
  float* op = out + rowi * HS + dg * 8;
  *(float4*)(op) = make_float4(o[0] * invl, o[1] * invl, o[2] * invl, o[3] * invl);
  *(float4*)(op + 4) = make_float4(o[4] * invl, o[5] * invl, o[6] * invl, o[7] * invl);
}

// ---------------------------------------------------------------------------
extern "C" void kernel_launch(void* const* d_in, const int* in_sizes, int n_in,
                              void* d_out, int out_size, void* d_ws,
                              size_t ws_size, hipStream_t stream) {
  const float* x = (const float*)d_in[0];
  const float* Wq = (const float*)d_in[1];
  const float* Wk = (const float*)d_in[2];
  const float* Wv = (const float*)d_in[3];
  float* out = (float*)d_out;

  float* wsf = (float*)d_ws;
  // Region 0..33.55MB: pacc (attn phase) overlaps selection-phase scratch
  // (xsum, rs, flag, wbf), all dead before attn_mfma runs.
  float* pacc = wsf;                         // 8,388,608 f (BB*KSEL*NSPL*HS)
  float* xsum = wsf;                         // 4,096 f (atomic accum)
  float* rs = xsum + 4096;                   // 16,384 f
  int* flag = (int*)(rs + 16384);            // 16,384 i
  unsigned short* wbf = (unsigned short*)(flag + 16384);  // 196,608 us
  // Past pacc: buffers live through attn.
  unsigned short* qbf = (unsigned short*)(pacc + 8388608);  // 1,048,576 us
  unsigned short* kbf = qbf + 1048576;       // 1,048,576 us
  unsigned short* vtbf = kbf + 1048576;      // 1,048,576 us
  int* idxp = (int*)(vtbf + 1048576);        // 8,192 i
  float* pl = (float*)(idxp + 8192);         // 131,072 f

  conv_w<<<96, 256, 0, stream>>>(Wq, Wk, Wv, wbf, xsum);
  fusedproj<<<512, 256, 0, stream>>>(x, wbf, xsum, qbf, kbf, vtbf);
  rowsums_x<<<256, 512, 0, stream>>>(x, Wq, Wk, xsum, rs);
  rankk<<<512, 256, 0, stream>>>(rs, flag);
  compact<<<BB, 256, 0, stream>>>(flag, idxp);
  attn_mfma<<<dim3(64, 4, BB), 256, 0, stream>>>(qbf, kbf, vtbf, idxp, pl, pacc);
  attn_combine<<<dim3(BB, 64), 256, 0, stream>>>(pl, pacc, idxp, out);
}